// Round 4
// baseline (1350.171 us; speedup 1.0000x reference)
//
#include <hip/hip_runtime.h>
#include <hip/hip_bf16.h>

// ---------------------------------------------------------------------------
// CGNN: 2 layers of { m = h[src]*e ; s = segment_mean(m,dst) ;
//                     [h, h_N] @ W + b (+ relu on layer 1) }
// Round 3: bucket-grouped edges (64 dst-nodes per bucket) instead of fully
// sorted CSR.
//   - bhist_kernel:   per-bucket edge histogram (LDS-staged)
//   - scan_kernel:    single-block exclusive scan -> boff / bcursor
//   - multisplit:     block-local LDS ranking + dense per-bucket appends
//                     (writes merge in L2 -> ~13 MB payload, low line amp)
//   - agg_bucket:     block per bucket, 64x64 fp32 accumulator in LDS,
//                     lane = feature, 8-edge ILP, native ds_add_f32 atomics,
//                     degree counted in LDS (kills count/offsets kernels)
//   - linear_sgpr:    thread per node, W via wave-uniform SGPR broadcast
// ---------------------------------------------------------------------------

#define F 64
#define NBMAX 2048          // max buckets LDS arrays support (need 1563)
#define EPT 32              // edges per thread in hist/multisplit
#define EPB (EPT * 256)     // edges per block = 8192

__global__ __launch_bounds__(256) void bhist_kernel(
    const int* __restrict__ dst, int* __restrict__ bcnt, int n_edges, int nb)
{
    __shared__ int lcnt[NBMAX];
    const int tid = threadIdx.x;
    for (int i = tid; i < nb; i += 256) lcnt[i] = 0;
    __syncthreads();

    const int e0 = blockIdx.x * EPB + tid;
#pragma unroll
    for (int k = 0; k < EPT; ++k) {
        const int e = e0 + k * 256;
        if (e < n_edges) atomicAdd(&lcnt[dst[e] >> 6], 1);
    }
    __syncthreads();
    for (int i = tid; i < nb; i += 256) {
        const int c = lcnt[i];
        if (c) atomicAdd(&bcnt[i], c);
    }
}

// Single block, 1024 threads: exclusive scan of bcnt into boff (nb+1) and
// bcursor (running cursors for multisplit).
__global__ __launch_bounds__(1024) void scan_kernel(
    const int* __restrict__ bcnt, int* __restrict__ boff,
    int* __restrict__ bcursor, int nb)
{
    __shared__ int wsum[16];
    __shared__ int carry_s;
    const int tid = threadIdx.x;
    if (tid == 0) carry_s = 0;
    __syncthreads();

    for (int c0 = 0; c0 < nb; c0 += 1024) {
        const int i = c0 + tid;
        const int c = (i < nb) ? bcnt[i] : 0;
        int v = c;
        for (int d = 1; d < 64; d <<= 1) {
            int t = __shfl_up(v, d, 64);
            if ((tid & 63) >= d) v += t;
        }
        const int wid = tid >> 6;
        if ((tid & 63) == 63) wsum[wid] = v;
        __syncthreads();
        if (tid < 16) {
            int t = wsum[tid];
            for (int d = 1; d < 16; d <<= 1) {
                int u = __shfl_up(t, d, 16);
                if (tid >= d) t += u;
            }
            wsum[tid] = t;
        }
        __syncthreads();
        const int carry = carry_s;
        const int incl  = carry + ((wid > 0) ? wsum[wid - 1] : 0) + v;
        if (i < nb) {
            boff[i + 1]  = incl;
            bcursor[i]   = incl - c;
            if (i == 0) boff[0] = 0;
        }
        __syncthreads();
        if (tid == 1023) carry_s = incl;  // carry + chunk total
        __syncthreads();
    }
}

// Block-local multisplit: rank 8192 edges in LDS, reserve per-bucket ranges
// with ONE global atomic per non-empty bucket, write records densely.
// rec.x = (local_dst << 20) | src,  rec.y = bits(edge_feat).
__global__ __launch_bounds__(256) void multisplit_kernel(
    const int* __restrict__ src, const int* __restrict__ dst,
    const float* __restrict__ ef, int* __restrict__ bcursor,
    int2* __restrict__ brec, int n_edges, int nb)
{
    __shared__ int lcnt[NBMAX];
    __shared__ int lbase[NBMAX];
    const int tid = threadIdx.x;
    for (int i = tid; i < nb; i += 256) lcnt[i] = 0;
    __syncthreads();

    const int e0 = blockIdx.x * EPB + tid;
    int d[EPT], rk[EPT];
#pragma unroll
    for (int k = 0; k < EPT; ++k) {
        const int e = e0 + k * 256;
        const int dd = (e < n_edges) ? dst[e] : -1;
        d[k]  = dd;
        rk[k] = (dd >= 0) ? atomicAdd(&lcnt[dd >> 6], 1) : 0;
    }
    __syncthreads();
    for (int i = tid; i < nb; i += 256) {
        const int c = lcnt[i];
        lbase[i] = c ? atomicAdd(&bcursor[i], c) : 0;
    }
    __syncthreads();
#pragma unroll
    for (int k = 0; k < EPT; ++k) {
        const int e = e0 + k * 256;
        if (e < n_edges) {
            const int dd  = d[k];
            const int pos = lbase[dd >> 6] + rk[k];
            brec[pos] = make_int2(((dd & 63) << 20) | src[e],
                                  __float_as_int(ef[e]));
        }
    }
}

// One block per bucket (64 dst nodes). LDS 64x64 fp32 accumulator,
// lane = feature. 8-edge ILP chunks per wave; ds_add_f32 accumulate.
// Degree counted in LDS -> s = acc / max(deg,1) written once, coalesced.
__global__ __launch_bounds__(256) void agg_bucket_kernel(
    const float* __restrict__ h, const int2* __restrict__ brec,
    const int* __restrict__ boff, float* __restrict__ s, int n_nodes)
{
    __shared__ float acc[64][64];
    __shared__ int   dcnt[64];
    const int b    = blockIdx.x;
    const int tid  = threadIdx.x;
    const int lane = tid & 63;
    const int wv   = tid >> 6;

    float4* accv = (float4*)acc;
    for (int i = tid; i < 64 * 16; i += 256)
        accv[i] = make_float4(0.f, 0.f, 0.f, 0.f);
    if (tid < 64) dcnt[tid] = 0;
    __syncthreads();

    const int e0 = boff[b];
    const int e1 = boff[b + 1];

    // degree pass (brec range is L2/L3-resident, 64-lane parallel)
    for (int e = e0 + tid; e < e1; e += 256)
        atomicAdd(&dcnt[brec[e].x >> 20], 1);

    // main pass: wave wv owns 8-edge chunks at e0 + wv*8 + 32*t
    int e = e0 + (wv << 3);
    for (; e + 8 <= e1; e += 32) {
        int2  r[8];
        float v[8];
#pragma unroll
        for (int k = 0; k < 8; ++k) r[k] = brec[e + k];
#pragma unroll
        for (int k = 0; k < 8; ++k)
            v[k] = h[(size_t)(r[k].x & 0xFFFFF) * F + lane] *
                   __int_as_float(r[k].y);
#pragma unroll
        for (int k = 0; k < 8; ++k)
            atomicAdd(&acc[r[k].x >> 20][lane], v[k]);
    }
    // tail: remaining < 8 edges of this wave's window
#pragma unroll
    for (int k = 0; k < 8; ++k) {
        const int ee = e + k;
        if (ee < e1) {
            const int2  r = brec[ee];
            const float v = h[(size_t)(r.x & 0xFFFFF) * F + lane] *
                            __int_as_float(r.y);
            atomicAdd(&acc[r.x >> 20][lane], v);
        }
    }
    __syncthreads();

    const int base = b << 6;
    for (int l = wv; l < 64; l += 4) {
        const int node = base + l;
        if (node < n_nodes) {
            const float id = 1.0f / fmaxf((float)dcnt[l], 1.0f);
            s[(size_t)node * F + lane] = acc[l][lane] * id;
        }
    }
}

// Thread per node. out[n,j] = act( sum_k x[n,k]*W[k,j] + b[j] ),
// x = concat(h[n,:], s[n,:]). W/b accesses are wave-uniform -> SGPR s_load.
template <int OUT, bool RELU>
__global__ __launch_bounds__(256) void linear_sgpr_kernel(
    const float* __restrict__ hin, const float* __restrict__ s,
    const float* __restrict__ W, const float* __restrict__ b,
    float* __restrict__ out, int n_nodes)
{
    const int node_raw = blockIdx.x * 256 + threadIdx.x;
    const int node = node_raw < n_nodes ? node_raw : n_nodes - 1;

    float acc[OUT];
#pragma unroll
    for (int j = 0; j < OUT; ++j) acc[j] = b[j];

    const float* __restrict__ hrow = hin + (size_t)node * F;
    const float* __restrict__ srow = s   + (size_t)node * F;

    for (int k4 = 0; k4 < F / 4; ++k4) {
        const float4 xh = *(const float4*)&hrow[k4 * 4];
        const float4 xs = *(const float4*)&srow[k4 * 4];
#pragma unroll
        for (int kk = 0; kk < 4; ++kk) {
            const int k = k4 * 4 + kk;
            const float xhk = ((const float*)&xh)[kk];
            const float xsk = ((const float*)&xs)[kk];
#pragma unroll
            for (int j = 0; j < OUT; ++j)
                acc[j] = fmaf(xhk, W[k * OUT + j], acc[j]);
#pragma unroll
            for (int j = 0; j < OUT; ++j)
                acc[j] = fmaf(xsk, W[(F + k) * OUT + j], acc[j]);
        }
    }

    if (node_raw < n_nodes) {
#pragma unroll
        for (int j = 0; j < OUT; ++j) {
            float v = acc[j];
            if (RELU) v = fmaxf(v, 0.f);
            out[(size_t)node * OUT + j] = v;
        }
    }
}

extern "C" void kernel_launch(void* const* d_in, const int* in_sizes, int n_in,
                              void* d_out, int out_size, void* d_ws, size_t ws_size,
                              hipStream_t stream)
{
    const float* in_feat   = (const float*)d_in[0];
    const float* edge_feat = (const float*)d_in[1];
    const int*   src       = (const int*)d_in[2];
    const int*   dst       = (const int*)d_in[3];
    const float* W1        = (const float*)d_in[4];
    const float* b1        = (const float*)d_in[5];
    const float* W2        = (const float*)d_in[6];
    const float* b2        = (const float*)d_in[7];
    float*       out       = (float*)d_out;

    const int n_nodes = in_sizes[0] / F;
    const int n_edges = in_sizes[2];
    const int nb      = (n_nodes + 63) >> 6;  // 64-node buckets

    // workspace layout (4-byte units)
    int*   wsi     = (int*)d_ws;
    int*   bcnt    = wsi;                 // [nb]        @ 0
    int*   boff    = wsi + 2048;          // [nb+1]      @ 2048
    int*   bcursor = wsi + 4096;          // [nb]        @ 4096
    int2*  brec    = (int2*)(wsi + 6144); // [n_edges]   (8B aligned)
    float* s       = (float*)(wsi + 6144 + 2 * (size_t)n_edges);
    float* h1      = s + (size_t)n_nodes * F;

    hipMemsetAsync(bcnt, 0, (size_t)nb * sizeof(int), stream);

    const int egrid = (n_edges + EPB - 1) / EPB;  // 196
    bhist_kernel<<<egrid, 256, 0, stream>>>(dst, bcnt, n_edges, nb);
    scan_kernel<<<1, 1024, 0, stream>>>(bcnt, boff, bcursor, nb);
    multisplit_kernel<<<egrid, 256, 0, stream>>>(src, dst, edge_feat,
                                                 bcursor, brec, n_edges, nb);

    const int lgrid = (n_nodes + 255) / 256;

    // ---- layer 1 ----
    agg_bucket_kernel<<<nb, 256, 0, stream>>>(in_feat, brec, boff, s, n_nodes);
    linear_sgpr_kernel<64, true><<<lgrid, 256, 0, stream>>>(in_feat, s, W1, b1, h1, n_nodes);

    // ---- layer 2 ----
    agg_bucket_kernel<<<nb, 256, 0, stream>>>(h1, brec, boff, s, n_nodes);
    linear_sgpr_kernel<32, false><<<lgrid, 256, 0, stream>>>(h1, s, W2, b2, out, n_nodes);
}

// Round 5
// 278.348 us; speedup vs baseline: 4.8507x; 4.8507x over previous
//
#include <hip/hip_runtime.h>
#include <hip/hip_bf16.h>

// ---------------------------------------------------------------------------
// CGNN: 2 layers of { m = h[src]*e ; s = segment_mean(m,dst) ;
//                     [h, h_N] @ W + b (+ relu on layer 1) }
// Round 4: two-phase edge reorder (bucket multisplit + in-place bucket sort)
// feeding the proven wave-per-node gather aggregation.
//   - bhist:       per-bucket (64 nodes) histogram, LDS-staged
//   - scan:        single-block scan -> boff / bcursor
//   - multisplit:  block-local LDS rank, dense per-bucket runs (low write amp)
//   - bucket_sort: block per bucket, LDS staging, exact per-node CSR order
//                  IN PLACE; emits off2[n+1] and invdeg (kills count/offsets)
//   - agg_kernel:  wave per node, 8 edges in flight x 8 lanes x 2 float4,
//                  masked tail, register accumulate, shfl_xor reduce
//   - linear_sgpr: thread per node, W via wave-uniform SGPR broadcast
// ---------------------------------------------------------------------------

#define F 64
#define NBMAX 2048          // bucket arrays sized for up to 2048 buckets
#define EPT 32              // edges per thread in hist/multisplit
#define EPB (EPT * 256)     // edges per block = 8192
#define BSMAX 2048          // max records per bucket staged in LDS (mean 1024)

__global__ __launch_bounds__(256) void bhist_kernel(
    const int* __restrict__ dst, int* __restrict__ bcnt, int n_edges, int nb)
{
    __shared__ int lcnt[NBMAX];
    const int tid = threadIdx.x;
    for (int i = tid; i < nb; i += 256) lcnt[i] = 0;
    __syncthreads();

    const int e0 = blockIdx.x * EPB + tid;
#pragma unroll
    for (int k = 0; k < EPT; ++k) {
        const int e = e0 + k * 256;
        if (e < n_edges) atomicAdd(&lcnt[dst[e] >> 6], 1);
    }
    __syncthreads();
    for (int i = tid; i < nb; i += 256) {
        const int c = lcnt[i];
        if (c) atomicAdd(&bcnt[i], c);
    }
}

// Single block: exclusive scan of bcnt into boff (nb+1 entries) + bcursor.
__global__ __launch_bounds__(1024) void scan_kernel(
    const int* __restrict__ bcnt, int* __restrict__ boff,
    int* __restrict__ bcursor, int nb)
{
    __shared__ int wsum[16];
    __shared__ int carry_s;
    const int tid = threadIdx.x;
    if (tid == 0) carry_s = 0;
    __syncthreads();

    for (int c0 = 0; c0 < nb; c0 += 1024) {
        const int i = c0 + tid;
        const int c = (i < nb) ? bcnt[i] : 0;
        int v = c;
        for (int d = 1; d < 64; d <<= 1) {
            int t = __shfl_up(v, d, 64);
            if ((tid & 63) >= d) v += t;
        }
        const int wid = tid >> 6;
        if ((tid & 63) == 63) wsum[wid] = v;
        __syncthreads();
        if (tid < 16) {
            int t = wsum[tid];
            for (int d = 1; d < 16; d <<= 1) {
                int u = __shfl_up(t, d, 16);
                if (tid >= d) t += u;
            }
            wsum[tid] = t;
        }
        __syncthreads();
        const int carry = carry_s;
        const int incl  = carry + ((wid > 0) ? wsum[wid - 1] : 0) + v;
        if (i < nb) {
            boff[i + 1] = incl;
            bcursor[i]  = incl - c;
            if (i == 0) boff[0] = 0;
        }
        __syncthreads();
        if (tid == 1023) carry_s = incl;
        __syncthreads();
    }
}

// Block-local multisplit: rank 8192 edges in LDS, reserve per-bucket ranges
// with one global atomic per non-empty bucket, write dense per-bucket runs.
// rec.x = (local_dst << 20) | src,  rec.y = bits(edge_feat).
__global__ __launch_bounds__(256) void multisplit_kernel(
    const int* __restrict__ src, const int* __restrict__ dst,
    const float* __restrict__ ef, int* __restrict__ bcursor,
    int2* __restrict__ brec, int n_edges, int nb)
{
    __shared__ int lcnt[NBMAX];
    __shared__ int lbase[NBMAX];
    const int tid = threadIdx.x;
    for (int i = tid; i < nb; i += 256) lcnt[i] = 0;
    __syncthreads();

    const int e0 = blockIdx.x * EPB + tid;
    int d[EPT], rk[EPT];
#pragma unroll
    for (int k = 0; k < EPT; ++k) {
        const int e = e0 + k * 256;
        const int dd = (e < n_edges) ? dst[e] : -1;
        d[k]  = dd;
        rk[k] = (dd >= 0) ? atomicAdd(&lcnt[dd >> 6], 1) : 0;
    }
    __syncthreads();
    for (int i = tid; i < nb; i += 256) {
        const int c = lcnt[i];
        lbase[i] = c ? atomicAdd(&bcursor[i], c) : 0;
    }
    __syncthreads();
#pragma unroll
    for (int k = 0; k < EPT; ++k) {
        const int e = e0 + k * 256;
        if (e < n_edges) {
            const int dd  = d[k];
            const int pos = lbase[dd >> 6] + rk[k];
            brec[pos] = make_int2(((dd & 63) << 20) | src[e],
                                  __float_as_int(ef[e]));
        }
    }
}

// Block per bucket: stage records in LDS, 64-counter histogram + wave scan,
// write back IN PLACE at exact per-node positions (contiguous window).
// Emits off2 (global CSR offsets) and invdeg. Output rec .x = src only.
__global__ __launch_bounds__(256) void bucket_sort_kernel(
    int2* __restrict__ brec, const int* __restrict__ boff,
    int* __restrict__ off2, float* __restrict__ invdeg, int n_nodes, int nb)
{
    __shared__ int2 stage[BSMAX];
    __shared__ int  lcnt[64];
    __shared__ int  lcur[64];

    const int b   = blockIdx.x;
    const int tid = threadIdx.x;
    const int e0  = boff[b];
    const int e1  = boff[b + 1];
    const int cnt = e1 - e0;

    if (tid < 64) lcnt[tid] = 0;
    __syncthreads();

    for (int i = tid; i < cnt; i += 256) {
        const int2 r = brec[e0 + i];
        stage[i] = r;
        atomicAdd(&lcnt[r.x >> 20], 1);
    }
    __syncthreads();

    if (tid < 64) {
        const int c = lcnt[tid];
        int v = c;
        for (int d = 1; d < 64; d <<= 1) {
            int t = __shfl_up(v, d, 64);
            if (tid >= d) v += t;
        }
        const int excl = v - c;
        lcur[tid] = excl;
        const int node = (b << 6) + tid;
        if (node < n_nodes) {
            off2[node]   = e0 + excl;
            invdeg[node] = 1.0f / fmaxf((float)c, 1.0f);
        }
    }
    if (tid == 0 && b == nb - 1) off2[n_nodes] = e1;
    __syncthreads();

    for (int i = tid; i < cnt; i += 256) {
        const int2 r   = stage[i];
        const int  pos = atomicAdd(&lcur[r.x >> 20], 1);
        brec[e0 + pos] = make_int2(r.x & 0xFFFFF, r.y);
    }
}

// Wave per node. lane = 8*g + q: g = edge slot (8 in flight), q = feature
// octet (2 x float4 per lane). Masked tail iteration, shfl_xor reduce over g.
__global__ __launch_bounds__(256) void agg_kernel(
    const float* __restrict__ h, const int2* __restrict__ rec,
    const int* __restrict__ off, const float* __restrict__ invdeg,
    float* __restrict__ s, int n_nodes)
{
    const int gid  = blockIdx.x * 256 + threadIdx.x;
    const int node = gid >> 6;
    if (node >= n_nodes) return;
    const int lane = threadIdx.x & 63;
    const int g = lane >> 3;   // 0..7
    const int q = lane & 7;    // 0..7

    const int e0 = off[node];
    const int e1 = off[node + 1];
    const int niter = (e1 - e0 + 7) >> 3;

    float4 a0 = make_float4(0.f, 0.f, 0.f, 0.f);
    float4 a1 = make_float4(0.f, 0.f, 0.f, 0.f);

    for (int it = 0; it < niter; ++it) {
        const int  e     = e0 + it * 8 + g;
        const bool valid = e < e1;
        const int2 r  = rec[valid ? e : e0];
        const float ev = valid ? __int_as_float(r.y) : 0.f;
        const float* __restrict__ row = h + (size_t)r.x * F + q * 8;
        const float4 x0 = *(const float4*)row;
        const float4 x1 = *(const float4*)(row + 4);
        a0.x = fmaf(x0.x, ev, a0.x); a0.y = fmaf(x0.y, ev, a0.y);
        a0.z = fmaf(x0.z, ev, a0.z); a0.w = fmaf(x0.w, ev, a0.w);
        a1.x = fmaf(x1.x, ev, a1.x); a1.y = fmaf(x1.y, ev, a1.y);
        a1.z = fmaf(x1.z, ev, a1.z); a1.w = fmaf(x1.w, ev, a1.w);
    }

#pragma unroll
    for (int m = 8; m < 64; m <<= 1) {
        a0.x += __shfl_xor(a0.x, m); a0.y += __shfl_xor(a0.y, m);
        a0.z += __shfl_xor(a0.z, m); a0.w += __shfl_xor(a0.w, m);
        a1.x += __shfl_xor(a1.x, m); a1.y += __shfl_xor(a1.y, m);
        a1.z += __shfl_xor(a1.z, m); a1.w += __shfl_xor(a1.w, m);
    }

    if (g == 0) {
        const float id = invdeg[node];
        float* __restrict__ srow = s + (size_t)node * F + q * 8;
        *(float4*)srow = make_float4(a0.x * id, a0.y * id, a0.z * id, a0.w * id);
        *(float4*)(srow + 4) = make_float4(a1.x * id, a1.y * id, a1.z * id, a1.w * id);
    }
}

// Thread per node. out[n,j] = act( sum_k x[n,k]*W[k,j] + b[j] ),
// x = concat(h[n,:], s[n,:]). W/b accesses are wave-uniform -> SGPR s_load.
template <int OUT, bool RELU>
__global__ __launch_bounds__(256) void linear_sgpr_kernel(
    const float* __restrict__ hin, const float* __restrict__ s,
    const float* __restrict__ W, const float* __restrict__ b,
    float* __restrict__ out, int n_nodes)
{
    const int node_raw = blockIdx.x * 256 + threadIdx.x;
    const int node = node_raw < n_nodes ? node_raw : n_nodes - 1;

    float acc[OUT];
#pragma unroll
    for (int j = 0; j < OUT; ++j) acc[j] = b[j];

    const float* __restrict__ hrow = hin + (size_t)node * F;
    const float* __restrict__ srow = s   + (size_t)node * F;

    for (int k4 = 0; k4 < F / 4; ++k4) {
        const float4 xh = *(const float4*)&hrow[k4 * 4];
        const float4 xs = *(const float4*)&srow[k4 * 4];
#pragma unroll
        for (int kk = 0; kk < 4; ++kk) {
            const int k = k4 * 4 + kk;
            const float xhk = ((const float*)&xh)[kk];
            const float xsk = ((const float*)&xs)[kk];
#pragma unroll
            for (int j = 0; j < OUT; ++j)
                acc[j] = fmaf(xhk, W[k * OUT + j], acc[j]);
#pragma unroll
            for (int j = 0; j < OUT; ++j)
                acc[j] = fmaf(xsk, W[(F + k) * OUT + j], acc[j]);
        }
    }

    if (node_raw < n_nodes) {
#pragma unroll
        for (int j = 0; j < OUT; ++j) {
            float v = acc[j];
            if (RELU) v = fmaxf(v, 0.f);
            out[(size_t)node * OUT + j] = v;
        }
    }
}

extern "C" void kernel_launch(void* const* d_in, const int* in_sizes, int n_in,
                              void* d_out, int out_size, void* d_ws, size_t ws_size,
                              hipStream_t stream)
{
    const float* in_feat   = (const float*)d_in[0];
    const float* edge_feat = (const float*)d_in[1];
    const int*   src       = (const int*)d_in[2];
    const int*   dst       = (const int*)d_in[3];
    const float* W1        = (const float*)d_in[4];
    const float* b1        = (const float*)d_in[5];
    const float* W2        = (const float*)d_in[6];
    const float* b2        = (const float*)d_in[7];
    float*       out       = (float*)d_out;

    const int n_nodes = in_sizes[0] / F;
    const int n_edges = in_sizes[2];
    const int nb      = (n_nodes + 63) >> 6;  // 64-node buckets

    // workspace layout (4-byte units)
    const int S = 100352;  // >= n_nodes+1, multiple of 256
    int*   wsi     = (int*)d_ws;
    int*   bcnt    = wsi;                     // [nb]
    int*   boff    = wsi + 2048;              // [nb+1]
    int*   bcursor = wsi + 4096;              // [nb]
    int*   off2    = wsi + 6144;              // [n_nodes+1]
    float* invdeg  = (float*)(wsi + 6144 + S);            // [n_nodes]
    int2*  brec    = (int2*)(wsi + 6144 + 2 * S);         // [n_edges]
    float* s       = (float*)(wsi + 6144 + 2 * S + 2 * (size_t)n_edges);
    float* h1      = s + (size_t)n_nodes * F;

    hipMemsetAsync(bcnt, 0, (size_t)nb * sizeof(int), stream);

    const int egrid = (n_edges + EPB - 1) / EPB;
    bhist_kernel<<<egrid, 256, 0, stream>>>(dst, bcnt, n_edges, nb);
    scan_kernel<<<1, 1024, 0, stream>>>(bcnt, boff, bcursor, nb);
    multisplit_kernel<<<egrid, 256, 0, stream>>>(src, dst, edge_feat,
                                                 bcursor, brec, n_edges, nb);
    bucket_sort_kernel<<<nb, 256, 0, stream>>>(brec, boff, off2, invdeg,
                                               n_nodes, nb);

    const int agrid = (int)(((size_t)n_nodes * 64 + 255) / 256);
    const int lgrid = (n_nodes + 255) / 256;

    // ---- layer 1 ----
    agg_kernel<<<agrid, 256, 0, stream>>>(in_feat, brec, off2, invdeg, s, n_nodes);
    linear_sgpr_kernel<64, true><<<lgrid, 256, 0, stream>>>(in_feat, s, W1, b1, h1, n_nodes);

    // ---- layer 2 ----
    agg_kernel<<<agrid, 256, 0, stream>>>(h1, brec, off2, invdeg, s, n_nodes);
    linear_sgpr_kernel<32, false><<<lgrid, 256, 0, stream>>>(h1, s, W2, b2, out, n_nodes);
}

// Round 6
// 264.342 us; speedup vs baseline: 5.1077x; 1.0530x over previous
//
#include <hip/hip_runtime.h>
#include <hip/hip_bf16.h>

// ---------------------------------------------------------------------------
// CGNN: 2 layers of { m = h[src]*e ; s = segment_mean(m,dst) ;
//                     [h, h_N] @ W + b (+ relu on layer 1) }
// Round 5: linear layer re-parallelized.
//   - reorder chain (bhist / scan / multisplit / bucket_sort) unchanged
//   - agg_kernel unchanged (wave per node, 8-edge ILP, masked tail)
//   - linear_wave_kernel: block = 64 nodes x 4 waves; wave wv computes
//     output cols [wv*OUT/4, ...): 4x the waves (6/SIMD, latency hidden),
//     W/b stay wave-uniform (s_load), x rows L1-shared across the 4 waves.
// ---------------------------------------------------------------------------

#define F 64
#define NBMAX 2048          // bucket arrays sized for up to 2048 buckets
#define EPT 32              // edges per thread in hist/multisplit
#define EPB (EPT * 256)     // edges per block = 8192
#define BSMAX 2048          // max records per bucket staged in LDS

__global__ __launch_bounds__(256) void bhist_kernel(
    const int* __restrict__ dst, int* __restrict__ bcnt, int n_edges, int nb)
{
    __shared__ int lcnt[NBMAX];
    const int tid = threadIdx.x;
    for (int i = tid; i < nb; i += 256) lcnt[i] = 0;
    __syncthreads();

    const int e0 = blockIdx.x * EPB + tid;
#pragma unroll
    for (int k = 0; k < EPT; ++k) {
        const int e = e0 + k * 256;
        if (e < n_edges) atomicAdd(&lcnt[dst[e] >> 6], 1);
    }
    __syncthreads();
    for (int i = tid; i < nb; i += 256) {
        const int c = lcnt[i];
        if (c) atomicAdd(&bcnt[i], c);
    }
}

// Single block: exclusive scan of bcnt into boff (nb+1 entries) + bcursor.
__global__ __launch_bounds__(1024) void scan_kernel(
    const int* __restrict__ bcnt, int* __restrict__ boff,
    int* __restrict__ bcursor, int nb)
{
    __shared__ int wsum[16];
    __shared__ int carry_s;
    const int tid = threadIdx.x;
    if (tid == 0) carry_s = 0;
    __syncthreads();

    for (int c0 = 0; c0 < nb; c0 += 1024) {
        const int i = c0 + tid;
        const int c = (i < nb) ? bcnt[i] : 0;
        int v = c;
        for (int d = 1; d < 64; d <<= 1) {
            int t = __shfl_up(v, d, 64);
            if ((tid & 63) >= d) v += t;
        }
        const int wid = tid >> 6;
        if ((tid & 63) == 63) wsum[wid] = v;
        __syncthreads();
        if (tid < 16) {
            int t = wsum[tid];
            for (int d = 1; d < 16; d <<= 1) {
                int u = __shfl_up(t, d, 16);
                if (tid >= d) t += u;
            }
            wsum[tid] = t;
        }
        __syncthreads();
        const int carry = carry_s;
        const int incl  = carry + ((wid > 0) ? wsum[wid - 1] : 0) + v;
        if (i < nb) {
            boff[i + 1] = incl;
            bcursor[i]  = incl - c;
            if (i == 0) boff[0] = 0;
        }
        __syncthreads();
        if (tid == 1023) carry_s = incl;
        __syncthreads();
    }
}

// Block-local multisplit: rank 8192 edges in LDS, reserve per-bucket ranges
// with one global atomic per non-empty bucket, write dense per-bucket runs.
// rec.x = (local_dst << 20) | src,  rec.y = bits(edge_feat).
__global__ __launch_bounds__(256) void multisplit_kernel(
    const int* __restrict__ src, const int* __restrict__ dst,
    const float* __restrict__ ef, int* __restrict__ bcursor,
    int2* __restrict__ brec, int n_edges, int nb)
{
    __shared__ int lcnt[NBMAX];
    __shared__ int lbase[NBMAX];
    const int tid = threadIdx.x;
    for (int i = tid; i < nb; i += 256) lcnt[i] = 0;
    __syncthreads();

    const int e0 = blockIdx.x * EPB + tid;
    int d[EPT], rk[EPT];
#pragma unroll
    for (int k = 0; k < EPT; ++k) {
        const int e = e0 + k * 256;
        const int dd = (e < n_edges) ? dst[e] : -1;
        d[k]  = dd;
        rk[k] = (dd >= 0) ? atomicAdd(&lcnt[dd >> 6], 1) : 0;
    }
    __syncthreads();
    for (int i = tid; i < nb; i += 256) {
        const int c = lcnt[i];
        lbase[i] = c ? atomicAdd(&bcursor[i], c) : 0;
    }
    __syncthreads();
#pragma unroll
    for (int k = 0; k < EPT; ++k) {
        const int e = e0 + k * 256;
        if (e < n_edges) {
            const int dd  = d[k];
            const int pos = lbase[dd >> 6] + rk[k];
            brec[pos] = make_int2(((dd & 63) << 20) | src[e],
                                  __float_as_int(ef[e]));
        }
    }
}

// Block per bucket: stage records in LDS, 64-counter histogram + wave scan,
// write back IN PLACE at exact per-node positions (contiguous window).
// Emits off2 (global CSR offsets) and invdeg. Output rec .x = src only.
__global__ __launch_bounds__(256) void bucket_sort_kernel(
    int2* __restrict__ brec, const int* __restrict__ boff,
    int* __restrict__ off2, float* __restrict__ invdeg, int n_nodes, int nb)
{
    __shared__ int2 stage[BSMAX];
    __shared__ int  lcnt[64];
    __shared__ int  lcur[64];

    const int b   = blockIdx.x;
    const int tid = threadIdx.x;
    const int e0  = boff[b];
    const int e1  = boff[b + 1];
    const int cnt = e1 - e0;

    if (tid < 64) lcnt[tid] = 0;
    __syncthreads();

    for (int i = tid; i < cnt; i += 256) {
        const int2 r = brec[e0 + i];
        stage[i] = r;
        atomicAdd(&lcnt[r.x >> 20], 1);
    }
    __syncthreads();

    if (tid < 64) {
        const int c = lcnt[tid];
        int v = c;
        for (int d = 1; d < 64; d <<= 1) {
            int t = __shfl_up(v, d, 64);
            if (tid >= d) v += t;
        }
        const int excl = v - c;
        lcur[tid] = excl;
        const int node = (b << 6) + tid;
        if (node < n_nodes) {
            off2[node]   = e0 + excl;
            invdeg[node] = 1.0f / fmaxf((float)c, 1.0f);
        }
    }
    if (tid == 0 && b == nb - 1) off2[n_nodes] = e1;
    __syncthreads();

    for (int i = tid; i < cnt; i += 256) {
        const int2 r   = stage[i];
        const int  pos = atomicAdd(&lcur[r.x >> 20], 1);
        brec[e0 + pos] = make_int2(r.x & 0xFFFFF, r.y);
    }
}

// Wave per node. lane = 8*g + q: g = edge slot (8 in flight), q = feature
// octet (2 x float4 per lane). Masked tail iteration, shfl_xor reduce over g.
__global__ __launch_bounds__(256) void agg_kernel(
    const float* __restrict__ h, const int2* __restrict__ rec,
    const int* __restrict__ off, const float* __restrict__ invdeg,
    float* __restrict__ s, int n_nodes)
{
    const int gid  = blockIdx.x * 256 + threadIdx.x;
    const int node = gid >> 6;
    if (node >= n_nodes) return;
    const int lane = threadIdx.x & 63;
    const int g = lane >> 3;   // 0..7
    const int q = lane & 7;    // 0..7

    const int e0 = off[node];
    const int e1 = off[node + 1];
    const int niter = (e1 - e0 + 7) >> 3;

    float4 a0 = make_float4(0.f, 0.f, 0.f, 0.f);
    float4 a1 = make_float4(0.f, 0.f, 0.f, 0.f);

    for (int it = 0; it < niter; ++it) {
        const int  e     = e0 + it * 8 + g;
        const bool valid = e < e1;
        const int2 r  = rec[valid ? e : e0];
        const float ev = valid ? __int_as_float(r.y) : 0.f;
        const float* __restrict__ row = h + (size_t)r.x * F + q * 8;
        const float4 x0 = *(const float4*)row;
        const float4 x1 = *(const float4*)(row + 4);
        a0.x = fmaf(x0.x, ev, a0.x); a0.y = fmaf(x0.y, ev, a0.y);
        a0.z = fmaf(x0.z, ev, a0.z); a0.w = fmaf(x0.w, ev, a0.w);
        a1.x = fmaf(x1.x, ev, a1.x); a1.y = fmaf(x1.y, ev, a1.y);
        a1.z = fmaf(x1.z, ev, a1.z); a1.w = fmaf(x1.w, ev, a1.w);
    }

#pragma unroll
    for (int m = 8; m < 64; m <<= 1) {
        a0.x += __shfl_xor(a0.x, m); a0.y += __shfl_xor(a0.y, m);
        a0.z += __shfl_xor(a0.z, m); a0.w += __shfl_xor(a0.w, m);
        a1.x += __shfl_xor(a1.x, m); a1.y += __shfl_xor(a1.y, m);
        a1.z += __shfl_xor(a1.z, m); a1.w += __shfl_xor(a1.w, m);
    }

    if (g == 0) {
        const float id = invdeg[node];
        float* __restrict__ srow = s + (size_t)node * F + q * 8;
        *(float4*)srow = make_float4(a0.x * id, a0.y * id, a0.z * id, a0.w * id);
        *(float4*)(srow + 4) = make_float4(a1.x * id, a1.y * id, a1.z * id, a1.w * id);
    }
}

// Block = 64 nodes x 4 waves. Wave wv computes output cols
// [wv*OUT/4, (wv+1)*OUT/4) for all 64 nodes (lane = node).
// W/b indices wave-uniform (readfirstlane-pinned) -> SGPR s_load path;
// the 4 waves share the same x rows via the CU's L1.
template <int OUT, bool RELU>
__global__ __launch_bounds__(256) void linear_wave_kernel(
    const float* __restrict__ hin, const float* __restrict__ s,
    const float* __restrict__ W, const float* __restrict__ b,
    float* __restrict__ out, int n_nodes)
{
    constexpr int JT = OUT / 4;          // j-tile per wave: 16 (lin1) / 8 (lin2)
    const int lane     = threadIdx.x & 63;
    const int node_raw = blockIdx.x * 64 + lane;
    const int node     = node_raw < n_nodes ? node_raw : n_nodes - 1;
    const int j0 = __builtin_amdgcn_readfirstlane((threadIdx.x >> 6) * JT);

    float acc[JT];
#pragma unroll
    for (int j = 0; j < JT; ++j) acc[j] = b[j0 + j];

    const float* __restrict__ hrow = hin + (size_t)node * F;
    const float* __restrict__ srow = s   + (size_t)node * F;

    for (int k4 = 0; k4 < F / 4; ++k4) {
        const float4 xh = *(const float4*)&hrow[k4 * 4];
        const float4 xs = *(const float4*)&srow[k4 * 4];
#pragma unroll
        for (int kk = 0; kk < 4; ++kk) {
            const int k = k4 * 4 + kk;
            const float xhk = ((const float*)&xh)[kk];
            const float xsk = ((const float*)&xs)[kk];
#pragma unroll
            for (int j = 0; j < JT; ++j)
                acc[j] = fmaf(xhk, W[k * OUT + j0 + j], acc[j]);
#pragma unroll
            for (int j = 0; j < JT; ++j)
                acc[j] = fmaf(xsk, W[(F + k) * OUT + j0 + j], acc[j]);
        }
    }

    if (node_raw < n_nodes) {
#pragma unroll
        for (int j = 0; j < JT; ++j) {
            float v = acc[j];
            if (RELU) v = fmaxf(v, 0.f);
            out[(size_t)node * OUT + j0 + j] = v;
        }
    }
}

extern "C" void kernel_launch(void* const* d_in, const int* in_sizes, int n_in,
                              void* d_out, int out_size, void* d_ws, size_t ws_size,
                              hipStream_t stream)
{
    const float* in_feat   = (const float*)d_in[0];
    const float* edge_feat = (const float*)d_in[1];
    const int*   src       = (const int*)d_in[2];
    const int*   dst       = (const int*)d_in[3];
    const float* W1        = (const float*)d_in[4];
    const float* b1        = (const float*)d_in[5];
    const float* W2        = (const float*)d_in[6];
    const float* b2        = (const float*)d_in[7];
    float*       out       = (float*)d_out;

    const int n_nodes = in_sizes[0] / F;
    const int n_edges = in_sizes[2];
    const int nb      = (n_nodes + 63) >> 6;  // 64-node buckets

    // workspace layout (4-byte units)
    const int S = 100352;  // >= n_nodes+1, multiple of 256
    int*   wsi     = (int*)d_ws;
    int*   bcnt    = wsi;                     // [nb]
    int*   boff    = wsi + 2048;              // [nb+1]
    int*   bcursor = wsi + 4096;              // [nb]
    int*   off2    = wsi + 6144;              // [n_nodes+1]
    float* invdeg  = (float*)(wsi + 6144 + S);            // [n_nodes]
    int2*  brec    = (int2*)(wsi + 6144 + 2 * S);         // [n_edges]
    float* s       = (float*)(wsi + 6144 + 2 * S + 2 * (size_t)n_edges);
    float* h1      = s + (size_t)n_nodes * F;

    hipMemsetAsync(bcnt, 0, (size_t)nb * sizeof(int), stream);

    const int egrid = (n_edges + EPB - 1) / EPB;
    bhist_kernel<<<egrid, 256, 0, stream>>>(dst, bcnt, n_edges, nb);
    scan_kernel<<<1, 1024, 0, stream>>>(bcnt, boff, bcursor, nb);
    multisplit_kernel<<<egrid, 256, 0, stream>>>(src, dst, edge_feat,
                                                 bcursor, brec, n_edges, nb);
    bucket_sort_kernel<<<nb, 256, 0, stream>>>(brec, boff, off2, invdeg,
                                               n_nodes, nb);

    const int agrid = (int)(((size_t)n_nodes * 64 + 255) / 256);
    const int lgrid = (n_nodes + 63) / 64;

    // ---- layer 1 ----
    agg_kernel<<<agrid, 256, 0, stream>>>(in_feat, brec, off2, invdeg, s, n_nodes);
    linear_wave_kernel<64, true><<<lgrid, 256, 0, stream>>>(in_feat, s, W1, b1, h1, n_nodes);

    // ---- layer 2 ----
    agg_kernel<<<agrid, 256, 0, stream>>>(h1, brec, off2, invdeg, s, n_nodes);
    linear_wave_kernel<32, false><<<lgrid, 256, 0, stream>>>(h1, s, W2, b2, out, n_nodes);
}

// Round 7
// 250.133 us; speedup vs baseline: 5.3978x; 1.0568x over previous
//
#include <hip/hip_runtime.h>
#include <hip/hip_bf16.h>

// ---------------------------------------------------------------------------
// CGNN: 2 layers of { m = h[src]*e ; s = segment_mean(m,dst) ;
//                     [h, h_N] @ W + b (+ relu on layer 1) }
// Round 6: bf16 shadow table for the aggregation gather.
//   - reorder chain (bhist / scan / multisplit / bucket_sort) unchanged
//   - f32_to_bf16_kernel: RNE-convert node table to bf16 (halves gather bytes)
//   - agg_kernel: wave per node, 8-edge ILP, ONE dwordx4 per lane per edge
//     (8 bf16 feats), unpack via bit-ops, fp32 FMA accumulate
//   - linear_wave_kernel unchanged (4 waves split OUT cols, W via s_load)
// ---------------------------------------------------------------------------

#define F 64
#define NBMAX 2048          // bucket arrays sized for up to 2048 buckets
#define EPT 32              // edges per thread in hist/multisplit
#define EPB (EPT * 256)     // edges per block = 8192
#define BSMAX 2048          // max records per bucket staged in LDS

__global__ __launch_bounds__(256) void bhist_kernel(
    const int* __restrict__ dst, int* __restrict__ bcnt, int n_edges, int nb)
{
    __shared__ int lcnt[NBMAX];
    const int tid = threadIdx.x;
    for (int i = tid; i < nb; i += 256) lcnt[i] = 0;
    __syncthreads();

    const int e0 = blockIdx.x * EPB + tid;
#pragma unroll
    for (int k = 0; k < EPT; ++k) {
        const int e = e0 + k * 256;
        if (e < n_edges) atomicAdd(&lcnt[dst[e] >> 6], 1);
    }
    __syncthreads();
    for (int i = tid; i < nb; i += 256) {
        const int c = lcnt[i];
        if (c) atomicAdd(&bcnt[i], c);
    }
}

// Single block: exclusive scan of bcnt into boff (nb+1 entries) + bcursor.
__global__ __launch_bounds__(1024) void scan_kernel(
    const int* __restrict__ bcnt, int* __restrict__ boff,
    int* __restrict__ bcursor, int nb)
{
    __shared__ int wsum[16];
    __shared__ int carry_s;
    const int tid = threadIdx.x;
    if (tid == 0) carry_s = 0;
    __syncthreads();

    for (int c0 = 0; c0 < nb; c0 += 1024) {
        const int i = c0 + tid;
        const int c = (i < nb) ? bcnt[i] : 0;
        int v = c;
        for (int d = 1; d < 64; d <<= 1) {
            int t = __shfl_up(v, d, 64);
            if ((tid & 63) >= d) v += t;
        }
        const int wid = tid >> 6;
        if ((tid & 63) == 63) wsum[wid] = v;
        __syncthreads();
        if (tid < 16) {
            int t = wsum[tid];
            for (int d = 1; d < 16; d <<= 1) {
                int u = __shfl_up(t, d, 16);
                if (tid >= d) t += u;
            }
            wsum[tid] = t;
        }
        __syncthreads();
        const int carry = carry_s;
        const int incl  = carry + ((wid > 0) ? wsum[wid - 1] : 0) + v;
        if (i < nb) {
            boff[i + 1] = incl;
            bcursor[i]  = incl - c;
            if (i == 0) boff[0] = 0;
        }
        __syncthreads();
        if (tid == 1023) carry_s = incl;
        __syncthreads();
    }
}

// Block-local multisplit: rank 8192 edges in LDS, reserve per-bucket ranges
// with one global atomic per non-empty bucket, write dense per-bucket runs.
// rec.x = (local_dst << 20) | src,  rec.y = bits(edge_feat).
__global__ __launch_bounds__(256) void multisplit_kernel(
    const int* __restrict__ src, const int* __restrict__ dst,
    const float* __restrict__ ef, int* __restrict__ bcursor,
    int2* __restrict__ brec, int n_edges, int nb)
{
    __shared__ int lcnt[NBMAX];
    __shared__ int lbase[NBMAX];
    const int tid = threadIdx.x;
    for (int i = tid; i < nb; i += 256) lcnt[i] = 0;
    __syncthreads();

    const int e0 = blockIdx.x * EPB + tid;
    int d[EPT], rk[EPT];
#pragma unroll
    for (int k = 0; k < EPT; ++k) {
        const int e = e0 + k * 256;
        const int dd = (e < n_edges) ? dst[e] : -1;
        d[k]  = dd;
        rk[k] = (dd >= 0) ? atomicAdd(&lcnt[dd >> 6], 1) : 0;
    }
    __syncthreads();
    for (int i = tid; i < nb; i += 256) {
        const int c = lcnt[i];
        lbase[i] = c ? atomicAdd(&bcursor[i], c) : 0;
    }
    __syncthreads();
#pragma unroll
    for (int k = 0; k < EPT; ++k) {
        const int e = e0 + k * 256;
        if (e < n_edges) {
            const int dd  = d[k];
            const int pos = lbase[dd >> 6] + rk[k];
            brec[pos] = make_int2(((dd & 63) << 20) | src[e],
                                  __float_as_int(ef[e]));
        }
    }
}

// Block per bucket: stage records in LDS, 64-counter histogram + wave scan,
// write back IN PLACE at exact per-node positions (contiguous window).
// Emits off2 (global CSR offsets) and invdeg. Output rec .x = src only.
__global__ __launch_bounds__(256) void bucket_sort_kernel(
    int2* __restrict__ brec, const int* __restrict__ boff,
    int* __restrict__ off2, float* __restrict__ invdeg, int n_nodes, int nb)
{
    __shared__ int2 stage[BSMAX];
    __shared__ int  lcnt[64];
    __shared__ int  lcur[64];

    const int b   = blockIdx.x;
    const int tid = threadIdx.x;
    const int e0  = boff[b];
    const int e1  = boff[b + 1];
    const int cnt = e1 - e0;

    if (tid < 64) lcnt[tid] = 0;
    __syncthreads();

    for (int i = tid; i < cnt; i += 256) {
        const int2 r = brec[e0 + i];
        stage[i] = r;
        atomicAdd(&lcnt[r.x >> 20], 1);
    }
    __syncthreads();

    if (tid < 64) {
        const int c = lcnt[tid];
        int v = c;
        for (int d = 1; d < 64; d <<= 1) {
            int t = __shfl_up(v, d, 64);
            if (tid >= d) v += t;
        }
        const int excl = v - c;
        lcur[tid] = excl;
        const int node = (b << 6) + tid;
        if (node < n_nodes) {
            off2[node]   = e0 + excl;
            invdeg[node] = 1.0f / fmaxf((float)c, 1.0f);
        }
    }
    if (tid == 0 && b == nb - 1) off2[n_nodes] = e1;
    __syncthreads();

    for (int i = tid; i < cnt; i += 256) {
        const int2 r   = stage[i];
        const int  pos = atomicAdd(&lcur[r.x >> 20], 1);
        brec[e0 + pos] = make_int2(r.x & 0xFFFFF, r.y);
    }
}

// RNE-convert fp32 array to packed bf16 (8 elems / thread).
__global__ __launch_bounds__(256) void f32_to_bf16_kernel(
    const float* __restrict__ x, unsigned short* __restrict__ y, int n8)
{
    const int i = blockIdx.x * 256 + threadIdx.x;
    if (i >= n8) return;
    const float4 a = ((const float4*)x)[2 * i];
    const float4 b = ((const float4*)x)[2 * i + 1];
    uint4 o;
#define CVT2(f0, f1, dstw)                                          \
    {                                                               \
        unsigned u0 = __float_as_uint(f0), u1 = __float_as_uint(f1);\
        u0 = (u0 + 0x7FFFu + ((u0 >> 16) & 1u)) >> 16;              \
        u1 = (u1 + 0x7FFFu + ((u1 >> 16) & 1u)) >> 16;              \
        dstw = u0 | (u1 << 16);                                     \
    }
    CVT2(a.x, a.y, o.x)
    CVT2(a.z, a.w, o.y)
    CVT2(b.x, b.y, o.z)
    CVT2(b.z, b.w, o.w)
#undef CVT2
    ((uint4*)y)[i] = o;
}

// Wave per node. lane = 8*g + q: g = edge slot (8 in flight), q = feature
// octet. Gathers from the bf16 shadow table: ONE dwordx4 (8 bf16) per lane
// per edge, unpacked with bit-ops, fp32 FMA. Masked tail, shfl_xor reduce.
__global__ __launch_bounds__(256) void agg_kernel(
    const unsigned short* __restrict__ hb, const int2* __restrict__ rec,
    const int* __restrict__ off, const float* __restrict__ invdeg,
    float* __restrict__ s, int n_nodes)
{
    const int gid  = blockIdx.x * 256 + threadIdx.x;
    const int node = gid >> 6;
    if (node >= n_nodes) return;
    const int lane = threadIdx.x & 63;
    const int g = lane >> 3;   // 0..7
    const int q = lane & 7;    // 0..7

    const int e0 = off[node];
    const int e1 = off[node + 1];
    const int niter = (e1 - e0 + 7) >> 3;

    float4 a0 = make_float4(0.f, 0.f, 0.f, 0.f);
    float4 a1 = make_float4(0.f, 0.f, 0.f, 0.f);

    for (int it = 0; it < niter; ++it) {
        const int  e     = e0 + it * 8 + g;
        const bool valid = e < e1;
        const int2 r  = rec[valid ? e : e0];
        const float ev = valid ? __int_as_float(r.y) : 0.f;
        const uint4 xv = *(const uint4*)(hb + (size_t)r.x * F + q * 8);
        const float x0 = __uint_as_float(xv.x << 16);
        const float x1 = __uint_as_float(xv.x & 0xFFFF0000u);
        const float x2 = __uint_as_float(xv.y << 16);
        const float x3 = __uint_as_float(xv.y & 0xFFFF0000u);
        const float x4 = __uint_as_float(xv.z << 16);
        const float x5 = __uint_as_float(xv.z & 0xFFFF0000u);
        const float x6 = __uint_as_float(xv.w << 16);
        const float x7 = __uint_as_float(xv.w & 0xFFFF0000u);
        a0.x = fmaf(x0, ev, a0.x); a0.y = fmaf(x1, ev, a0.y);
        a0.z = fmaf(x2, ev, a0.z); a0.w = fmaf(x3, ev, a0.w);
        a1.x = fmaf(x4, ev, a1.x); a1.y = fmaf(x5, ev, a1.y);
        a1.z = fmaf(x6, ev, a1.z); a1.w = fmaf(x7, ev, a1.w);
    }

#pragma unroll
    for (int m = 8; m < 64; m <<= 1) {
        a0.x += __shfl_xor(a0.x, m); a0.y += __shfl_xor(a0.y, m);
        a0.z += __shfl_xor(a0.z, m); a0.w += __shfl_xor(a0.w, m);
        a1.x += __shfl_xor(a1.x, m); a1.y += __shfl_xor(a1.y, m);
        a1.z += __shfl_xor(a1.z, m); a1.w += __shfl_xor(a1.w, m);
    }

    if (g == 0) {
        const float id = invdeg[node];
        float* __restrict__ srow = s + (size_t)node * F + q * 8;
        *(float4*)srow = make_float4(a0.x * id, a0.y * id, a0.z * id, a0.w * id);
        *(float4*)(srow + 4) = make_float4(a1.x * id, a1.y * id, a1.z * id, a1.w * id);
    }
}

// Block = 64 nodes x 4 waves. Wave wv computes output cols
// [wv*OUT/4, (wv+1)*OUT/4) for all 64 nodes (lane = node).
// W/b indices wave-uniform (readfirstlane-pinned) -> SGPR s_load path;
// the 4 waves share the same x rows via the CU's L1.
template <int OUT, bool RELU>
__global__ __launch_bounds__(256) void linear_wave_kernel(
    const float* __restrict__ hin, const float* __restrict__ s,
    const float* __restrict__ W, const float* __restrict__ b,
    float* __restrict__ out, int n_nodes)
{
    constexpr int JT = OUT / 4;          // j-tile per wave: 16 (lin1) / 8 (lin2)
    const int lane     = threadIdx.x & 63;
    const int node_raw = blockIdx.x * 64 + lane;
    const int node     = node_raw < n_nodes ? node_raw : n_nodes - 1;
    const int j0 = __builtin_amdgcn_readfirstlane((threadIdx.x >> 6) * JT);

    float acc[JT];
#pragma unroll
    for (int j = 0; j < JT; ++j) acc[j] = b[j0 + j];

    const float* __restrict__ hrow = hin + (size_t)node * F;
    const float* __restrict__ srow = s   + (size_t)node * F;

    for (int k4 = 0; k4 < F / 4; ++k4) {
        const float4 xh = *(const float4*)&hrow[k4 * 4];
        const float4 xs = *(const float4*)&srow[k4 * 4];
#pragma unroll
        for (int kk = 0; kk < 4; ++kk) {
            const int k = k4 * 4 + kk;
            const float xhk = ((const float*)&xh)[kk];
            const float xsk = ((const float*)&xs)[kk];
#pragma unroll
            for (int j = 0; j < JT; ++j)
                acc[j] = fmaf(xhk, W[k * OUT + j0 + j], acc[j]);
#pragma unroll
            for (int j = 0; j < JT; ++j)
                acc[j] = fmaf(xsk, W[(F + k) * OUT + j0 + j], acc[j]);
        }
    }

    if (node_raw < n_nodes) {
#pragma unroll
        for (int j = 0; j < JT; ++j) {
            float v = acc[j];
            if (RELU) v = fmaxf(v, 0.f);
            out[(size_t)node * OUT + j0 + j] = v;
        }
    }
}

extern "C" void kernel_launch(void* const* d_in, const int* in_sizes, int n_in,
                              void* d_out, int out_size, void* d_ws, size_t ws_size,
                              hipStream_t stream)
{
    const float* in_feat   = (const float*)d_in[0];
    const float* edge_feat = (const float*)d_in[1];
    const int*   src       = (const int*)d_in[2];
    const int*   dst       = (const int*)d_in[3];
    const float* W1        = (const float*)d_in[4];
    const float* b1        = (const float*)d_in[5];
    const float* W2        = (const float*)d_in[6];
    const float* b2        = (const float*)d_in[7];
    float*       out       = (float*)d_out;

    const int n_nodes = in_sizes[0] / F;
    const int n_edges = in_sizes[2];
    const int nb      = (n_nodes + 63) >> 6;  // 64-node buckets

    // workspace layout (4-byte units)
    const int S = 100352;  // >= n_nodes+1, multiple of 256
    int*   wsi     = (int*)d_ws;
    int*   bcnt    = wsi;                     // [nb]
    int*   boff    = wsi + 2048;              // [nb+1]
    int*   bcursor = wsi + 4096;              // [nb]
    int*   off2    = wsi + 6144;              // [n_nodes+1]
    float* invdeg  = (float*)(wsi + 6144 + S);            // [n_nodes]
    int2*  brec    = (int2*)(wsi + 6144 + 2 * S);         // [n_edges]
    float* s       = (float*)(wsi + 6144 + 2 * S + 2 * (size_t)n_edges);
    float* h1      = s + (size_t)n_nodes * F;             // [n*64] fp32
    unsigned short* hb = (unsigned short*)(h1 + (size_t)n_nodes * F); // [n*64] bf16

    hipMemsetAsync(bcnt, 0, (size_t)nb * sizeof(int), stream);

    const int egrid = (n_edges + EPB - 1) / EPB;
    bhist_kernel<<<egrid, 256, 0, stream>>>(dst, bcnt, n_edges, nb);
    scan_kernel<<<1, 1024, 0, stream>>>(bcnt, boff, bcursor, nb);
    multisplit_kernel<<<egrid, 256, 0, stream>>>(src, dst, edge_feat,
                                                 bcursor, brec, n_edges, nb);
    bucket_sort_kernel<<<nb, 256, 0, stream>>>(brec, boff, off2, invdeg,
                                               n_nodes, nb);

    const int n8    = (n_nodes * F) >> 3;               // elems/8
    const int cgrid = (n8 + 255) / 256;
    const int agrid = (int)(((size_t)n_nodes * 64 + 255) / 256);
    const int lgrid = (n_nodes + 63) / 64;

    // ---- layer 1 ----
    f32_to_bf16_kernel<<<cgrid, 256, 0, stream>>>(in_feat, hb, n8);
    agg_kernel<<<agrid, 256, 0, stream>>>(hb, brec, off2, invdeg, s, n_nodes);
    linear_wave_kernel<64, true><<<lgrid, 256, 0, stream>>>(in_feat, s, W1, b1, h1, n_nodes);

    // ---- layer 2 ----
    f32_to_bf16_kernel<<<cgrid, 256, 0, stream>>>(h1, hb, n8);
    agg_kernel<<<agrid, 256, 0, stream>>>(hb, brec, off2, invdeg, s, n_nodes);
    linear_wave_kernel<32, false><<<lgrid, 256, 0, stream>>>(h1, s, W2, b2, out, n_nodes);
}

// Round 8
// 239.396 us; speedup vs baseline: 5.6399x; 1.0448x over previous
//
#include <hip/hip_runtime.h>
#include <hip/hip_bf16.h>

// ---------------------------------------------------------------------------
// CGNN: 2 layers of { m = h[src]*e ; s = segment_mean(m,dst) ;
//                     [h, h_N] @ W + b (+ relu on layer 1) }
// Round 7: widen the reorder kernels for TLP.
//   - bhist / multisplit: 1024 threads x EPT=8 (was 256 x 32) -> 4x waves,
//     same EPB=8192 (keeps dense per-bucket runs / low write amp)
//   - scan, bucket_sort unchanged
//   - f32_to_bf16 + bf16-gather agg_kernel unchanged (round-6 win)
//   - linear_wave_kernel unchanged (round-5 win)
// ---------------------------------------------------------------------------

#define F 64
#define NBMAX 2048          // bucket arrays sized for up to 2048 buckets
#define EPT 8               // edges per thread in hist/multisplit
#define TPB 1024            // threads per block in hist/multisplit
#define EPB (EPT * TPB)     // edges per block = 8192
#define BSMAX 2048          // max records per bucket staged in LDS

__global__ __launch_bounds__(TPB) void bhist_kernel(
    const int* __restrict__ dst, int* __restrict__ bcnt, int n_edges, int nb)
{
    __shared__ int lcnt[NBMAX];
    const int tid = threadIdx.x;
    for (int i = tid; i < nb; i += TPB) lcnt[i] = 0;
    __syncthreads();

    const int e0 = blockIdx.x * EPB + tid;
#pragma unroll
    for (int k = 0; k < EPT; ++k) {
        const int e = e0 + k * TPB;
        if (e < n_edges) atomicAdd(&lcnt[dst[e] >> 6], 1);
    }
    __syncthreads();
    for (int i = tid; i < nb; i += TPB) {
        const int c = lcnt[i];
        if (c) atomicAdd(&bcnt[i], c);
    }
}

// Single block: exclusive scan of bcnt into boff (nb+1 entries) + bcursor.
__global__ __launch_bounds__(1024) void scan_kernel(
    const int* __restrict__ bcnt, int* __restrict__ boff,
    int* __restrict__ bcursor, int nb)
{
    __shared__ int wsum[16];
    __shared__ int carry_s;
    const int tid = threadIdx.x;
    if (tid == 0) carry_s = 0;
    __syncthreads();

    for (int c0 = 0; c0 < nb; c0 += 1024) {
        const int i = c0 + tid;
        const int c = (i < nb) ? bcnt[i] : 0;
        int v = c;
        for (int d = 1; d < 64; d <<= 1) {
            int t = __shfl_up(v, d, 64);
            if ((tid & 63) >= d) v += t;
        }
        const int wid = tid >> 6;
        if ((tid & 63) == 63) wsum[wid] = v;
        __syncthreads();
        if (tid < 16) {
            int t = wsum[tid];
            for (int d = 1; d < 16; d <<= 1) {
                int u = __shfl_up(t, d, 16);
                if (tid >= d) t += u;
            }
            wsum[tid] = t;
        }
        __syncthreads();
        const int carry = carry_s;
        const int incl  = carry + ((wid > 0) ? wsum[wid - 1] : 0) + v;
        if (i < nb) {
            boff[i + 1] = incl;
            bcursor[i]  = incl - c;
            if (i == 0) boff[0] = 0;
        }
        __syncthreads();
        if (tid == 1023) carry_s = incl;
        __syncthreads();
    }
}

// Block-local multisplit: rank 8192 edges in LDS, reserve per-bucket ranges
// with one global atomic per non-empty bucket, write dense per-bucket runs.
// rec.x = (local_dst << 20) | src,  rec.y = bits(edge_feat).
__global__ __launch_bounds__(TPB) void multisplit_kernel(
    const int* __restrict__ src, const int* __restrict__ dst,
    const float* __restrict__ ef, int* __restrict__ bcursor,
    int2* __restrict__ brec, int n_edges, int nb)
{
    __shared__ int lcnt[NBMAX];
    __shared__ int lbase[NBMAX];
    const int tid = threadIdx.x;
    for (int i = tid; i < nb; i += TPB) lcnt[i] = 0;
    __syncthreads();

    const int e0 = blockIdx.x * EPB + tid;
    int d[EPT], rk[EPT];
#pragma unroll
    for (int k = 0; k < EPT; ++k) {
        const int e = e0 + k * TPB;
        const int dd = (e < n_edges) ? dst[e] : -1;
        d[k]  = dd;
        rk[k] = (dd >= 0) ? atomicAdd(&lcnt[dd >> 6], 1) : 0;
    }
    __syncthreads();
    for (int i = tid; i < nb; i += TPB) {
        const int c = lcnt[i];
        lbase[i] = c ? atomicAdd(&bcursor[i], c) : 0;
    }
    __syncthreads();
#pragma unroll
    for (int k = 0; k < EPT; ++k) {
        const int e = e0 + k * TPB;
        if (e < n_edges) {
            const int dd  = d[k];
            const int pos = lbase[dd >> 6] + rk[k];
            brec[pos] = make_int2(((dd & 63) << 20) | src[e],
                                  __float_as_int(ef[e]));
        }
    }
}

// Block per bucket: stage records in LDS, 64-counter histogram + wave scan,
// write back IN PLACE at exact per-node positions (contiguous window).
// Emits off2 (global CSR offsets) and invdeg. Output rec .x = src only.
__global__ __launch_bounds__(256) void bucket_sort_kernel(
    int2* __restrict__ brec, const int* __restrict__ boff,
    int* __restrict__ off2, float* __restrict__ invdeg, int n_nodes, int nb)
{
    __shared__ int2 stage[BSMAX];
    __shared__ int  lcnt[64];
    __shared__ int  lcur[64];

    const int b   = blockIdx.x;
    const int tid = threadIdx.x;
    const int e0  = boff[b];
    const int e1  = boff[b + 1];
    const int cnt = e1 - e0;

    if (tid < 64) lcnt[tid] = 0;
    __syncthreads();

    for (int i = tid; i < cnt; i += 256) {
        const int2 r = brec[e0 + i];
        stage[i] = r;
        atomicAdd(&lcnt[r.x >> 20], 1);
    }
    __syncthreads();

    if (tid < 64) {
        const int c = lcnt[tid];
        int v = c;
        for (int d = 1; d < 64; d <<= 1) {
            int t = __shfl_up(v, d, 64);
            if (tid >= d) v += t;
        }
        const int excl = v - c;
        lcur[tid] = excl;
        const int node = (b << 6) + tid;
        if (node < n_nodes) {
            off2[node]   = e0 + excl;
            invdeg[node] = 1.0f / fmaxf((float)c, 1.0f);
        }
    }
    if (tid == 0 && b == nb - 1) off2[n_nodes] = e1;
    __syncthreads();

    for (int i = tid; i < cnt; i += 256) {
        const int2 r   = stage[i];
        const int  pos = atomicAdd(&lcur[r.x >> 20], 1);
        brec[e0 + pos] = make_int2(r.x & 0xFFFFF, r.y);
    }
}

// RNE-convert fp32 array to packed bf16 (8 elems / thread).
__global__ __launch_bounds__(256) void f32_to_bf16_kernel(
    const float* __restrict__ x, unsigned short* __restrict__ y, int n8)
{
    const int i = blockIdx.x * 256 + threadIdx.x;
    if (i >= n8) return;
    const float4 a = ((const float4*)x)[2 * i];
    const float4 b = ((const float4*)x)[2 * i + 1];
    uint4 o;
#define CVT2(f0, f1, dstw)                                          \
    {                                                               \
        unsigned u0 = __float_as_uint(f0), u1 = __float_as_uint(f1);\
        u0 = (u0 + 0x7FFFu + ((u0 >> 16) & 1u)) >> 16;              \
        u1 = (u1 + 0x7FFFu + ((u1 >> 16) & 1u)) >> 16;              \
        dstw = u0 | (u1 << 16);                                     \
    }
    CVT2(a.x, a.y, o.x)
    CVT2(a.z, a.w, o.y)
    CVT2(b.x, b.y, o.z)
    CVT2(b.z, b.w, o.w)
#undef CVT2
    ((uint4*)y)[i] = o;
}

// Wave per node. lane = 8*g + q: g = edge slot (8 in flight), q = feature
// octet. Gathers from the bf16 shadow table: ONE dwordx4 (8 bf16) per lane
// per edge, unpacked with bit-ops, fp32 FMA. Masked tail, shfl_xor reduce.
__global__ __launch_bounds__(256) void agg_kernel(
    const unsigned short* __restrict__ hb, const int2* __restrict__ rec,
    const int* __restrict__ off, const float* __restrict__ invdeg,
    float* __restrict__ s, int n_nodes)
{
    const int gid  = blockIdx.x * 256 + threadIdx.x;
    const int node = gid >> 6;
    if (node >= n_nodes) return;
    const int lane = threadIdx.x & 63;
    const int g = lane >> 3;   // 0..7
    const int q = lane & 7;    // 0..7

    const int e0 = off[node];
    const int e1 = off[node + 1];
    const int niter = (e1 - e0 + 7) >> 3;

    float4 a0 = make_float4(0.f, 0.f, 0.f, 0.f);
    float4 a1 = make_float4(0.f, 0.f, 0.f, 0.f);

    for (int it = 0; it < niter; ++it) {
        const int  e     = e0 + it * 8 + g;
        const bool valid = e < e1;
        const int2 r  = rec[valid ? e : e0];
        const float ev = valid ? __int_as_float(r.y) : 0.f;
        const uint4 xv = *(const uint4*)(hb + (size_t)r.x * F + q * 8);
        const float x0 = __uint_as_float(xv.x << 16);
        const float x1 = __uint_as_float(xv.x & 0xFFFF0000u);
        const float x2 = __uint_as_float(xv.y << 16);
        const float x3 = __uint_as_float(xv.y & 0xFFFF0000u);
        const float x4 = __uint_as_float(xv.z << 16);
        const float x5 = __uint_as_float(xv.z & 0xFFFF0000u);
        const float x6 = __uint_as_float(xv.w << 16);
        const float x7 = __uint_as_float(xv.w & 0xFFFF0000u);
        a0.x = fmaf(x0, ev, a0.x); a0.y = fmaf(x1, ev, a0.y);
        a0.z = fmaf(x2, ev, a0.z); a0.w = fmaf(x3, ev, a0.w);
        a1.x = fmaf(x4, ev, a1.x); a1.y = fmaf(x5, ev, a1.y);
        a1.z = fmaf(x6, ev, a1.z); a1.w = fmaf(x7, ev, a1.w);
    }

#pragma unroll
    for (int m = 8; m < 64; m <<= 1) {
        a0.x += __shfl_xor(a0.x, m); a0.y += __shfl_xor(a0.y, m);
        a0.z += __shfl_xor(a0.z, m); a0.w += __shfl_xor(a0.w, m);
        a1.x += __shfl_xor(a1.x, m); a1.y += __shfl_xor(a1.y, m);
        a1.z += __shfl_xor(a1.z, m); a1.w += __shfl_xor(a1.w, m);
    }

    if (g == 0) {
        const float id = invdeg[node];
        float* __restrict__ srow = s + (size_t)node * F + q * 8;
        *(float4*)srow = make_float4(a0.x * id, a0.y * id, a0.z * id, a0.w * id);
        *(float4*)(srow + 4) = make_float4(a1.x * id, a1.y * id, a1.z * id, a1.w * id);
    }
}

// Block = 64 nodes x 4 waves. Wave wv computes output cols
// [wv*OUT/4, (wv+1)*OUT/4) for all 64 nodes (lane = node).
// W/b indices wave-uniform (readfirstlane-pinned) -> SGPR s_load path;
// the 4 waves share the same x rows via the CU's L1.
template <int OUT, bool RELU>
__global__ __launch_bounds__(256) void linear_wave_kernel(
    const float* __restrict__ hin, const float* __restrict__ s,
    const float* __restrict__ W, const float* __restrict__ b,
    float* __restrict__ out, int n_nodes)
{
    constexpr int JT = OUT / 4;          // j-tile per wave: 16 (lin1) / 8 (lin2)
    const int lane     = threadIdx.x & 63;
    const int node_raw = blockIdx.x * 64 + lane;
    const int node     = node_raw < n_nodes ? node_raw : n_nodes - 1;
    const int j0 = __builtin_amdgcn_readfirstlane((threadIdx.x >> 6) * JT);

    float acc[JT];
#pragma unroll
    for (int j = 0; j < JT; ++j) acc[j] = b[j0 + j];

    const float* __restrict__ hrow = hin + (size_t)node * F;
    const float* __restrict__ srow = s   + (size_t)node * F;

    for (int k4 = 0; k4 < F / 4; ++k4) {
        const float4 xh = *(const float4*)&hrow[k4 * 4];
        const float4 xs = *(const float4*)&srow[k4 * 4];
#pragma unroll
        for (int kk = 0; kk < 4; ++kk) {
            const int k = k4 * 4 + kk;
            const float xhk = ((const float*)&xh)[kk];
            const float xsk = ((const float*)&xs)[kk];
#pragma unroll
            for (int j = 0; j < JT; ++j)
                acc[j] = fmaf(xhk, W[k * OUT + j0 + j], acc[j]);
#pragma unroll
            for (int j = 0; j < JT; ++j)
                acc[j] = fmaf(xsk, W[(F + k) * OUT + j0 + j], acc[j]);
        }
    }

    if (node_raw < n_nodes) {
#pragma unroll
        for (int j = 0; j < JT; ++j) {
            float v = acc[j];
            if (RELU) v = fmaxf(v, 0.f);
            out[(size_t)node * OUT + j0 + j] = v;
        }
    }
}

extern "C" void kernel_launch(void* const* d_in, const int* in_sizes, int n_in,
                              void* d_out, int out_size, void* d_ws, size_t ws_size,
                              hipStream_t stream)
{
    const float* in_feat   = (const float*)d_in[0];
    const float* edge_feat = (const float*)d_in[1];
    const int*   src       = (const int*)d_in[2];
    const int*   dst       = (const int*)d_in[3];
    const float* W1        = (const float*)d_in[4];
    const float* b1        = (const float*)d_in[5];
    const float* W2        = (const float*)d_in[6];
    const float* b2        = (const float*)d_in[7];
    float*       out       = (float*)d_out;

    const int n_nodes = in_sizes[0] / F;
    const int n_edges = in_sizes[2];
    const int nb      = (n_nodes + 63) >> 6;  // 64-node buckets

    // workspace layout (4-byte units)
    const int S = 100352;  // >= n_nodes+1, multiple of 256
    int*   wsi     = (int*)d_ws;
    int*   bcnt    = wsi;                     // [nb]
    int*   boff    = wsi + 2048;              // [nb+1]
    int*   bcursor = wsi + 4096;              // [nb]
    int*   off2    = wsi + 6144;              // [n_nodes+1]
    float* invdeg  = (float*)(wsi + 6144 + S);            // [n_nodes]
    int2*  brec    = (int2*)(wsi + 6144 + 2 * S);         // [n_edges]
    float* s       = (float*)(wsi + 6144 + 2 * S + 2 * (size_t)n_edges);
    float* h1      = s + (size_t)n_nodes * F;             // [n*64] fp32
    unsigned short* hb = (unsigned short*)(h1 + (size_t)n_nodes * F); // [n*64] bf16

    hipMemsetAsync(bcnt, 0, (size_t)nb * sizeof(int), stream);

    const int egrid = (n_edges + EPB - 1) / EPB;
    bhist_kernel<<<egrid, TPB, 0, stream>>>(dst, bcnt, n_edges, nb);
    scan_kernel<<<1, 1024, 0, stream>>>(bcnt, boff, bcursor, nb);
    multisplit_kernel<<<egrid, TPB, 0, stream>>>(src, dst, edge_feat,
                                                 bcursor, brec, n_edges, nb);
    bucket_sort_kernel<<<nb, 256, 0, stream>>>(brec, boff, off2, invdeg,
                                               n_nodes, nb);

    const int n8    = (n_nodes * F) >> 3;               // elems/8
    const int cgrid = (n8 + 255) / 256;
    const int agrid = (int)(((size_t)n_nodes * 64 + 255) / 256);
    const int lgrid = (n_nodes + 63) / 64;

    // ---- layer 1 ----
    f32_to_bf16_kernel<<<cgrid, 256, 0, stream>>>(in_feat, hb, n8);
    agg_kernel<<<agrid, 256, 0, stream>>>(hb, brec, off2, invdeg, s, n_nodes);
    linear_wave_kernel<64, true><<<lgrid, 256, 0, stream>>>(in_feat, s, W1, b1, h1, n_nodes);

    // ---- layer 2 ----
    f32_to_bf16_kernel<<<cgrid, 256, 0, stream>>>(h1, hb, n8);
    agg_kernel<<<agrid, 256, 0, stream>>>(hb, brec, off2, invdeg, s, n_nodes);
    linear_wave_kernel<32, false><<<lgrid, 256, 0, stream>>>(h1, s, W2, b2, out, n_nodes);
}

// Round 9
// 215.034 us; speedup vs baseline: 6.2789x; 1.1133x over previous
//
#include <hip/hip_runtime.h>
#include <hip/hip_bf16.h>

// ---------------------------------------------------------------------------
// CGNN: 2 layers of { m = h[src]*e ; s = segment_mean(m,dst) ;
//                     [h, h_N] @ W + b (+ relu on layer 1) }
// Round 8: linear layer via LDS-staged x (kills the 64-lines-per-load stall).
//   - reorder chain (bhist/scan/multisplit/bucket_sort) unchanged (r7 win)
//   - f32_to_bf16 + bf16-gather agg_kernel unchanged (r6 win)
//   - linear_lds_kernel: block = 64 nodes; coalesced float4 staging of
//     h|s rows into xin[64][132]; 4 waves split OUT cols (W via s_load);
//     x read from LDS (ds_read_b128). Linear1 also emits bf16 h1 for the
//     layer-2 gather -> second f32_to_bf16 pass eliminated.
// ---------------------------------------------------------------------------

#define F 64
#define NBMAX 2048          // bucket arrays sized for up to 2048 buckets
#define EPT 8               // edges per thread in hist/multisplit
#define TPB 1024            // threads per block in hist/multisplit
#define EPB (EPT * TPB)     // edges per block = 8192
#define BSMAX 2048          // max records per bucket staged in LDS

__global__ __launch_bounds__(TPB) void bhist_kernel(
    const int* __restrict__ dst, int* __restrict__ bcnt, int n_edges, int nb)
{
    __shared__ int lcnt[NBMAX];
    const int tid = threadIdx.x;
    for (int i = tid; i < nb; i += TPB) lcnt[i] = 0;
    __syncthreads();

    const int e0 = blockIdx.x * EPB + tid;
#pragma unroll
    for (int k = 0; k < EPT; ++k) {
        const int e = e0 + k * TPB;
        if (e < n_edges) atomicAdd(&lcnt[dst[e] >> 6], 1);
    }
    __syncthreads();
    for (int i = tid; i < nb; i += TPB) {
        const int c = lcnt[i];
        if (c) atomicAdd(&bcnt[i], c);
    }
}

// Single block: exclusive scan of bcnt into boff (nb+1 entries) + bcursor.
__global__ __launch_bounds__(1024) void scan_kernel(
    const int* __restrict__ bcnt, int* __restrict__ boff,
    int* __restrict__ bcursor, int nb)
{
    __shared__ int wsum[16];
    __shared__ int carry_s;
    const int tid = threadIdx.x;
    if (tid == 0) carry_s = 0;
    __syncthreads();

    for (int c0 = 0; c0 < nb; c0 += 1024) {
        const int i = c0 + tid;
        const int c = (i < nb) ? bcnt[i] : 0;
        int v = c;
        for (int d = 1; d < 64; d <<= 1) {
            int t = __shfl_up(v, d, 64);
            if ((tid & 63) >= d) v += t;
        }
        const int wid = tid >> 6;
        if ((tid & 63) == 63) wsum[wid] = v;
        __syncthreads();
        if (tid < 16) {
            int t = wsum[tid];
            for (int d = 1; d < 16; d <<= 1) {
                int u = __shfl_up(t, d, 16);
                if (tid >= d) t += u;
            }
            wsum[tid] = t;
        }
        __syncthreads();
        const int carry = carry_s;
        const int incl  = carry + ((wid > 0) ? wsum[wid - 1] : 0) + v;
        if (i < nb) {
            boff[i + 1] = incl;
            bcursor[i]  = incl - c;
            if (i == 0) boff[0] = 0;
        }
        __syncthreads();
        if (tid == 1023) carry_s = incl;
        __syncthreads();
    }
}

// Block-local multisplit: rank 8192 edges in LDS, reserve per-bucket ranges
// with one global atomic per non-empty bucket, write dense per-bucket runs.
// rec.x = (local_dst << 20) | src,  rec.y = bits(edge_feat).
__global__ __launch_bounds__(TPB) void multisplit_kernel(
    const int* __restrict__ src, const int* __restrict__ dst,
    const float* __restrict__ ef, int* __restrict__ bcursor,
    int2* __restrict__ brec, int n_edges, int nb)
{
    __shared__ int lcnt[NBMAX];
    __shared__ int lbase[NBMAX];
    const int tid = threadIdx.x;
    for (int i = tid; i < nb; i += TPB) lcnt[i] = 0;
    __syncthreads();

    const int e0 = blockIdx.x * EPB + tid;
    int d[EPT], rk[EPT];
#pragma unroll
    for (int k = 0; k < EPT; ++k) {
        const int e = e0 + k * TPB;
        const int dd = (e < n_edges) ? dst[e] : -1;
        d[k]  = dd;
        rk[k] = (dd >= 0) ? atomicAdd(&lcnt[dd >> 6], 1) : 0;
    }
    __syncthreads();
    for (int i = tid; i < nb; i += TPB) {
        const int c = lcnt[i];
        lbase[i] = c ? atomicAdd(&bcursor[i], c) : 0;
    }
    __syncthreads();
#pragma unroll
    for (int k = 0; k < EPT; ++k) {
        const int e = e0 + k * TPB;
        if (e < n_edges) {
            const int dd  = d[k];
            const int pos = lbase[dd >> 6] + rk[k];
            brec[pos] = make_int2(((dd & 63) << 20) | src[e],
                                  __float_as_int(ef[e]));
        }
    }
}

// Block per bucket: stage records in LDS, 64-counter histogram + wave scan,
// write back IN PLACE at exact per-node positions (contiguous window).
// Emits off2 (global CSR offsets) and invdeg. Output rec .x = src only.
__global__ __launch_bounds__(256) void bucket_sort_kernel(
    int2* __restrict__ brec, const int* __restrict__ boff,
    int* __restrict__ off2, float* __restrict__ invdeg, int n_nodes, int nb)
{
    __shared__ int2 stage[BSMAX];
    __shared__ int  lcnt[64];
    __shared__ int  lcur[64];

    const int b   = blockIdx.x;
    const int tid = threadIdx.x;
    const int e0  = boff[b];
    const int e1  = boff[b + 1];
    const int cnt = e1 - e0;

    if (tid < 64) lcnt[tid] = 0;
    __syncthreads();

    for (int i = tid; i < cnt; i += 256) {
        const int2 r = brec[e0 + i];
        stage[i] = r;
        atomicAdd(&lcnt[r.x >> 20], 1);
    }
    __syncthreads();

    if (tid < 64) {
        const int c = lcnt[tid];
        int v = c;
        for (int d = 1; d < 64; d <<= 1) {
            int t = __shfl_up(v, d, 64);
            if (tid >= d) v += t;
        }
        const int excl = v - c;
        lcur[tid] = excl;
        const int node = (b << 6) + tid;
        if (node < n_nodes) {
            off2[node]   = e0 + excl;
            invdeg[node] = 1.0f / fmaxf((float)c, 1.0f);
        }
    }
    if (tid == 0 && b == nb - 1) off2[n_nodes] = e1;
    __syncthreads();

    for (int i = tid; i < cnt; i += 256) {
        const int2 r   = stage[i];
        const int  pos = atomicAdd(&lcur[r.x >> 20], 1);
        brec[e0 + pos] = make_int2(r.x & 0xFFFFF, r.y);
    }
}

__device__ __forceinline__ unsigned bf16_rne(float f)
{
    unsigned u = __float_as_uint(f);
    return (u + 0x7FFFu + ((u >> 16) & 1u)) >> 16;
}

// RNE-convert fp32 array to packed bf16 (8 elems / thread).
__global__ __launch_bounds__(256) void f32_to_bf16_kernel(
    const float* __restrict__ x, unsigned short* __restrict__ y, int n8)
{
    const int i = blockIdx.x * 256 + threadIdx.x;
    if (i >= n8) return;
    const float4 a = ((const float4*)x)[2 * i];
    const float4 b = ((const float4*)x)[2 * i + 1];
    uint4 o;
    o.x = bf16_rne(a.x) | (bf16_rne(a.y) << 16);
    o.y = bf16_rne(a.z) | (bf16_rne(a.w) << 16);
    o.z = bf16_rne(b.x) | (bf16_rne(b.y) << 16);
    o.w = bf16_rne(b.z) | (bf16_rne(b.w) << 16);
    ((uint4*)y)[i] = o;
}

// Wave per node. lane = 8*g + q: g = edge slot (8 in flight), q = feature
// octet. Gathers from the bf16 shadow table: ONE dwordx4 (8 bf16) per lane
// per edge, unpacked with bit-ops, fp32 FMA. Masked tail, shfl_xor reduce.
__global__ __launch_bounds__(256) void agg_kernel(
    const unsigned short* __restrict__ hb, const int2* __restrict__ rec,
    const int* __restrict__ off, const float* __restrict__ invdeg,
    float* __restrict__ s, int n_nodes)
{
    const int gid  = blockIdx.x * 256 + threadIdx.x;
    const int node = gid >> 6;
    if (node >= n_nodes) return;
    const int lane = threadIdx.x & 63;
    const int g = lane >> 3;   // 0..7
    const int q = lane & 7;    // 0..7

    const int e0 = off[node];
    const int e1 = off[node + 1];
    const int niter = (e1 - e0 + 7) >> 3;

    float4 a0 = make_float4(0.f, 0.f, 0.f, 0.f);
    float4 a1 = make_float4(0.f, 0.f, 0.f, 0.f);

    for (int it = 0; it < niter; ++it) {
        const int  e     = e0 + it * 8 + g;
        const bool valid = e < e1;
        const int2 r  = rec[valid ? e : e0];
        const float ev = valid ? __int_as_float(r.y) : 0.f;
        const uint4 xv = *(const uint4*)(hb + (size_t)r.x * F + q * 8);
        const float x0 = __uint_as_float(xv.x << 16);
        const float x1 = __uint_as_float(xv.x & 0xFFFF0000u);
        const float x2 = __uint_as_float(xv.y << 16);
        const float x3 = __uint_as_float(xv.y & 0xFFFF0000u);
        const float x4 = __uint_as_float(xv.z << 16);
        const float x5 = __uint_as_float(xv.z & 0xFFFF0000u);
        const float x6 = __uint_as_float(xv.w << 16);
        const float x7 = __uint_as_float(xv.w & 0xFFFF0000u);
        a0.x = fmaf(x0, ev, a0.x); a0.y = fmaf(x1, ev, a0.y);
        a0.z = fmaf(x2, ev, a0.z); a0.w = fmaf(x3, ev, a0.w);
        a1.x = fmaf(x4, ev, a1.x); a1.y = fmaf(x5, ev, a1.y);
        a1.z = fmaf(x6, ev, a1.z); a1.w = fmaf(x7, ev, a1.w);
    }

#pragma unroll
    for (int m = 8; m < 64; m <<= 1) {
        a0.x += __shfl_xor(a0.x, m); a0.y += __shfl_xor(a0.y, m);
        a0.z += __shfl_xor(a0.z, m); a0.w += __shfl_xor(a0.w, m);
        a1.x += __shfl_xor(a1.x, m); a1.y += __shfl_xor(a1.y, m);
        a1.z += __shfl_xor(a1.z, m); a1.w += __shfl_xor(a1.w, m);
    }

    if (g == 0) {
        const float id = invdeg[node];
        float* __restrict__ srow = s + (size_t)node * F + q * 8;
        *(float4*)srow = make_float4(a0.x * id, a0.y * id, a0.z * id, a0.w * id);
        *(float4*)(srow + 4) = make_float4(a1.x * id, a1.y * id, a1.z * id, a1.w * id);
    }
}

// Block = 64 nodes x 4 waves. Stage x = [h|s] rows into LDS with coalesced
// float4 loads (consecutive threads -> consecutive addresses). Wave wv
// computes output cols [wv*JT, ...) for all 64 nodes (lane = node), reading
// x from LDS (ds_read_b128) and W via wave-uniform s_load.
// If EMIT_BF16, also writes the bf16 shadow row for the next layer's gather.
template <int OUT, bool RELU, bool EMIT_BF16>
__global__ __launch_bounds__(256) void linear_lds_kernel(
    const float* __restrict__ hin, const float* __restrict__ s,
    const float* __restrict__ W, const float* __restrict__ b,
    float* __restrict__ out, unsigned short* __restrict__ hb_out, int n_nodes)
{
    constexpr int JT  = OUT / 4;   // j-tile per wave: 16 (lin1) / 8 (lin2)
    constexpr int STR = 132;       // row stride in floats (128 + 4, 16B-aligned)
    __shared__ float xin[64 * STR];

    const int tid   = threadIdx.x;
    const int node0 = blockIdx.x * 64;

    // stage h-half: 64 rows x 16 float4 (rows contiguous in global -> coalesced)
    for (int i = tid; i < 1024; i += 256) {
        const int ln = i >> 4, c4 = i & 15;
        const int node = node0 + ln;
        float4 v = make_float4(0.f, 0.f, 0.f, 0.f);
        if (node < n_nodes) v = *(const float4*)&hin[(size_t)node * F + c4 * 4];
        *(float4*)&xin[ln * STR + c4 * 4] = v;
    }
    // stage s-half
    for (int i = tid; i < 1024; i += 256) {
        const int ln = i >> 4, c4 = i & 15;
        const int node = node0 + ln;
        float4 v = make_float4(0.f, 0.f, 0.f, 0.f);
        if (node < n_nodes) v = *(const float4*)&s[(size_t)node * F + c4 * 4];
        *(float4*)&xin[ln * STR + F + c4 * 4] = v;
    }
    __syncthreads();

    const int lane = tid & 63;
    const int j0   = __builtin_amdgcn_readfirstlane((tid >> 6) * JT);

    float acc[JT];
#pragma unroll
    for (int j = 0; j < JT; ++j) acc[j] = b[j0 + j];

    const float* __restrict__ xrow = &xin[lane * STR];
#pragma unroll 2
    for (int k4 = 0; k4 < 32; ++k4) {
        const float4 xv = *(const float4*)&xrow[k4 * 4];
#pragma unroll
        for (int kk = 0; kk < 4; ++kk) {
            const int   k  = k4 * 4 + kk;
            const float xk = ((const float*)&xv)[kk];
#pragma unroll
            for (int j = 0; j < JT; ++j)
                acc[j] = fmaf(xk, W[k * OUT + j0 + j], acc[j]);
        }
    }

    const int node = node0 + lane;
    if (node < n_nodes) {
#pragma unroll
        for (int j = 0; j < JT; ++j) {
            float v = acc[j];
            if (RELU) v = fmaxf(v, 0.f);
            acc[j] = v;
            out[(size_t)node * OUT + j0 + j] = v;
        }
        if (EMIT_BF16) {
            unsigned* __restrict__ hw =
                (unsigned*)(hb_out + (size_t)node * OUT + j0);
#pragma unroll
            for (int j = 0; j < JT; j += 2)
                hw[j >> 1] = bf16_rne(acc[j]) | (bf16_rne(acc[j + 1]) << 16);
        }
    }
}

extern "C" void kernel_launch(void* const* d_in, const int* in_sizes, int n_in,
                              void* d_out, int out_size, void* d_ws, size_t ws_size,
                              hipStream_t stream)
{
    const float* in_feat   = (const float*)d_in[0];
    const float* edge_feat = (const float*)d_in[1];
    const int*   src       = (const int*)d_in[2];
    const int*   dst       = (const int*)d_in[3];
    const float* W1        = (const float*)d_in[4];
    const float* b1        = (const float*)d_in[5];
    const float* W2        = (const float*)d_in[6];
    const float* b2        = (const float*)d_in[7];
    float*       out       = (float*)d_out;

    const int n_nodes = in_sizes[0] / F;
    const int n_edges = in_sizes[2];
    const int nb      = (n_nodes + 63) >> 6;  // 64-node buckets

    // workspace layout (4-byte units)
    const int S = 100352;  // >= n_nodes+1, multiple of 256
    int*   wsi     = (int*)d_ws;
    int*   bcnt    = wsi;                     // [nb]
    int*   boff    = wsi + 2048;              // [nb+1]
    int*   bcursor = wsi + 4096;              // [nb]
    int*   off2    = wsi + 6144;              // [n_nodes+1]
    float* invdeg  = (float*)(wsi + 6144 + S);            // [n_nodes]
    int2*  brec    = (int2*)(wsi + 6144 + 2 * S);         // [n_edges]
    float* s       = (float*)(wsi + 6144 + 2 * S + 2 * (size_t)n_edges);
    float* h1      = s + (size_t)n_nodes * F;             // [n*64] fp32
    unsigned short* hb = (unsigned short*)(h1 + (size_t)n_nodes * F); // [n*64] bf16

    hipMemsetAsync(bcnt, 0, (size_t)nb * sizeof(int), stream);

    const int egrid = (n_edges + EPB - 1) / EPB;
    bhist_kernel<<<egrid, TPB, 0, stream>>>(dst, bcnt, n_edges, nb);
    scan_kernel<<<1, 1024, 0, stream>>>(bcnt, boff, bcursor, nb);
    multisplit_kernel<<<egrid, TPB, 0, stream>>>(src, dst, edge_feat,
                                                 bcursor, brec, n_edges, nb);
    bucket_sort_kernel<<<nb, 256, 0, stream>>>(brec, boff, off2, invdeg,
                                               n_nodes, nb);

    const int n8    = (n_nodes * F) >> 3;               // elems/8
    const int cgrid = (n8 + 255) / 256;
    const int agrid = (int)(((size_t)n_nodes * 64 + 255) / 256);
    const int lgrid = (n_nodes + 63) / 64;

    // ---- layer 1 ----
    f32_to_bf16_kernel<<<cgrid, 256, 0, stream>>>(in_feat, hb, n8);
    agg_kernel<<<agrid, 256, 0, stream>>>(hb, brec, off2, invdeg, s, n_nodes);
    linear_lds_kernel<64, true, true><<<lgrid, 256, 0, stream>>>(
        in_feat, s, W1, b1, h1, hb, n_nodes);

    // ---- layer 2 ----
    agg_kernel<<<agrid, 256, 0, stream>>>(hb, brec, off2, invdeg, s, n_nodes);
    linear_lds_kernel<32, false, false><<<lgrid, 256, 0, stream>>>(
        h1, s, W2, b2, out, hb, n_nodes);
}

// Round 10
// 192.215 us; speedup vs baseline: 7.0243x; 1.1187x over previous
//
#include <hip/hip_runtime.h>
#include <hip/hip_bf16.h>

// ---------------------------------------------------------------------------
// CGNN: 2 layers of { m = h[src]*e ; s = segment_mean(m,dst) ;
//                     [h, h_N] @ W + b (+ relu on layer 1) }
// Round 9:
//   - agg_kernel v4: 16 edges in flight per wave (2 gathers/lane, dual
//     accumulators) -> 2x outstanding VMEM, halved loop trips
//   - h1 kept ONLY as bf16 (hb): lin1 emits bf16; lin2 stages h-half from
//     hb (unpack in LDS staging) -> 51 MB fp32 h1 traffic eliminated
//   - reorder chain, f32_to_bf16(in_feat), linear LDS structure unchanged
// ---------------------------------------------------------------------------

#define F 64
#define NBMAX 2048          // bucket arrays sized for up to 2048 buckets
#define EPT 8               // edges per thread in hist/multisplit
#define TPB 1024            // threads per block in hist/multisplit
#define EPB (EPT * TPB)     // edges per block = 8192
#define BSMAX 2048          // max records per bucket staged in LDS

__global__ __launch_bounds__(TPB) void bhist_kernel(
    const int* __restrict__ dst, int* __restrict__ bcnt, int n_edges, int nb)
{
    __shared__ int lcnt[NBMAX];
    const int tid = threadIdx.x;
    for (int i = tid; i < nb; i += TPB) lcnt[i] = 0;
    __syncthreads();

    const int e0 = blockIdx.x * EPB + tid;
#pragma unroll
    for (int k = 0; k < EPT; ++k) {
        const int e = e0 + k * TPB;
        if (e < n_edges) atomicAdd(&lcnt[dst[e] >> 6], 1);
    }
    __syncthreads();
    for (int i = tid; i < nb; i += TPB) {
        const int c = lcnt[i];
        if (c) atomicAdd(&bcnt[i], c);
    }
}

// Single block: exclusive scan of bcnt into boff (nb+1 entries) + bcursor.
__global__ __launch_bounds__(1024) void scan_kernel(
    const int* __restrict__ bcnt, int* __restrict__ boff,
    int* __restrict__ bcursor, int nb)
{
    __shared__ int wsum[16];
    __shared__ int carry_s;
    const int tid = threadIdx.x;
    if (tid == 0) carry_s = 0;
    __syncthreads();

    for (int c0 = 0; c0 < nb; c0 += 1024) {
        const int i = c0 + tid;
        const int c = (i < nb) ? bcnt[i] : 0;
        int v = c;
        for (int d = 1; d < 64; d <<= 1) {
            int t = __shfl_up(v, d, 64);
            if ((tid & 63) >= d) v += t;
        }
        const int wid = tid >> 6;
        if ((tid & 63) == 63) wsum[wid] = v;
        __syncthreads();
        if (tid < 16) {
            int t = wsum[tid];
            for (int d = 1; d < 16; d <<= 1) {
                int u = __shfl_up(t, d, 16);
                if (tid >= d) t += u;
            }
            wsum[tid] = t;
        }
        __syncthreads();
        const int carry = carry_s;
        const int incl  = carry + ((wid > 0) ? wsum[wid - 1] : 0) + v;
        if (i < nb) {
            boff[i + 1] = incl;
            bcursor[i]  = incl - c;
            if (i == 0) boff[0] = 0;
        }
        __syncthreads();
        if (tid == 1023) carry_s = incl;
        __syncthreads();
    }
}

// Block-local multisplit: rank 8192 edges in LDS, reserve per-bucket ranges
// with one global atomic per non-empty bucket, write dense per-bucket runs.
// rec.x = (local_dst << 20) | src,  rec.y = bits(edge_feat).
__global__ __launch_bounds__(TPB) void multisplit_kernel(
    const int* __restrict__ src, const int* __restrict__ dst,
    const float* __restrict__ ef, int* __restrict__ bcursor,
    int2* __restrict__ brec, int n_edges, int nb)
{
    __shared__ int lcnt[NBMAX];
    __shared__ int lbase[NBMAX];
    const int tid = threadIdx.x;
    for (int i = tid; i < nb; i += TPB) lcnt[i] = 0;
    __syncthreads();

    const int e0 = blockIdx.x * EPB + tid;
    int d[EPT], rk[EPT];
#pragma unroll
    for (int k = 0; k < EPT; ++k) {
        const int e = e0 + k * TPB;
        const int dd = (e < n_edges) ? dst[e] : -1;
        d[k]  = dd;
        rk[k] = (dd >= 0) ? atomicAdd(&lcnt[dd >> 6], 1) : 0;
    }
    __syncthreads();
    for (int i = tid; i < nb; i += TPB) {
        const int c = lcnt[i];
        lbase[i] = c ? atomicAdd(&bcursor[i], c) : 0;
    }
    __syncthreads();
#pragma unroll
    for (int k = 0; k < EPT; ++k) {
        const int e = e0 + k * TPB;
        if (e < n_edges) {
            const int dd  = d[k];
            const int pos = lbase[dd >> 6] + rk[k];
            brec[pos] = make_int2(((dd & 63) << 20) | src[e],
                                  __float_as_int(ef[e]));
        }
    }
}

// Block per bucket: stage records in LDS, 64-counter histogram + wave scan,
// write back IN PLACE at exact per-node positions (contiguous window).
// Emits off2 (global CSR offsets) and invdeg. Output rec .x = src only.
__global__ __launch_bounds__(256) void bucket_sort_kernel(
    int2* __restrict__ brec, const int* __restrict__ boff,
    int* __restrict__ off2, float* __restrict__ invdeg, int n_nodes, int nb)
{
    __shared__ int2 stage[BSMAX];
    __shared__ int  lcnt[64];
    __shared__ int  lcur[64];

    const int b   = blockIdx.x;
    const int tid = threadIdx.x;
    const int e0  = boff[b];
    const int e1  = boff[b + 1];
    const int cnt = e1 - e0;

    if (tid < 64) lcnt[tid] = 0;
    __syncthreads();

    for (int i = tid; i < cnt; i += 256) {
        const int2 r = brec[e0 + i];
        stage[i] = r;
        atomicAdd(&lcnt[r.x >> 20], 1);
    }
    __syncthreads();

    if (tid < 64) {
        const int c = lcnt[tid];
        int v = c;
        for (int d = 1; d < 64; d <<= 1) {
            int t = __shfl_up(v, d, 64);
            if (tid >= d) v += t;
        }
        const int excl = v - c;
        lcur[tid] = excl;
        const int node = (b << 6) + tid;
        if (node < n_nodes) {
            off2[node]   = e0 + excl;
            invdeg[node] = 1.0f / fmaxf((float)c, 1.0f);
        }
    }
    if (tid == 0 && b == nb - 1) off2[n_nodes] = e1;
    __syncthreads();

    for (int i = tid; i < cnt; i += 256) {
        const int2 r   = stage[i];
        const int  pos = atomicAdd(&lcur[r.x >> 20], 1);
        brec[e0 + pos] = make_int2(r.x & 0xFFFFF, r.y);
    }
}

__device__ __forceinline__ unsigned bf16_rne(float f)
{
    unsigned u = __float_as_uint(f);
    return (u + 0x7FFFu + ((u >> 16) & 1u)) >> 16;
}

// RNE-convert fp32 array to packed bf16 (8 elems / thread).
__global__ __launch_bounds__(256) void f32_to_bf16_kernel(
    const float* __restrict__ x, unsigned short* __restrict__ y, int n8)
{
    const int i = blockIdx.x * 256 + threadIdx.x;
    if (i >= n8) return;
    const float4 a = ((const float4*)x)[2 * i];
    const float4 b = ((const float4*)x)[2 * i + 1];
    uint4 o;
    o.x = bf16_rne(a.x) | (bf16_rne(a.y) << 16);
    o.y = bf16_rne(a.z) | (bf16_rne(a.w) << 16);
    o.z = bf16_rne(b.x) | (bf16_rne(b.y) << 16);
    o.w = bf16_rne(b.z) | (bf16_rne(b.w) << 16);
    ((uint4*)y)[i] = o;
}

// Wave per node. lane = 8*g + q. 16 edges in flight per iteration:
// slots A = base+g, B = base+8+g, each lane gathers 8 bf16 (dwordx4) per
// slot into independent accumulators. Masked tails, shfl_xor reduce over g.
__global__ __launch_bounds__(256) void agg_kernel(
    const unsigned short* __restrict__ hb, const int2* __restrict__ rec,
    const int* __restrict__ off, const float* __restrict__ invdeg,
    float* __restrict__ s, int n_nodes)
{
    const int gid  = blockIdx.x * 256 + threadIdx.x;
    const int node = gid >> 6;
    if (node >= n_nodes) return;
    const int lane = threadIdx.x & 63;
    const int g = lane >> 3;   // 0..7
    const int q = lane & 7;    // 0..7

    const int e0 = off[node];
    const int e1 = off[node + 1];
    const int niter = (e1 - e0 + 15) >> 4;

    float4 aA0 = make_float4(0.f, 0.f, 0.f, 0.f);
    float4 aA1 = make_float4(0.f, 0.f, 0.f, 0.f);
    float4 aB0 = make_float4(0.f, 0.f, 0.f, 0.f);
    float4 aB1 = make_float4(0.f, 0.f, 0.f, 0.f);

    for (int it = 0; it < niter; ++it) {
        const int  base = e0 + it * 16;
        const int  eA   = base + g;
        const int  eB   = base + 8 + g;
        const bool vA   = eA < e1;
        const bool vB   = eB < e1;
        const int2 rA = rec[vA ? eA : e0];
        const int2 rB = rec[vB ? eB : e0];
        const float evA = vA ? __int_as_float(rA.y) : 0.f;
        const float evB = vB ? __int_as_float(rB.y) : 0.f;
        const uint4 xA = *(const uint4*)(hb + (size_t)rA.x * F + q * 8);
        const uint4 xB = *(const uint4*)(hb + (size_t)rB.x * F + q * 8);

        aA0.x = fmaf(__uint_as_float(xA.x << 16),        evA, aA0.x);
        aA0.y = fmaf(__uint_as_float(xA.x & 0xFFFF0000u), evA, aA0.y);
        aA0.z = fmaf(__uint_as_float(xA.y << 16),        evA, aA0.z);
        aA0.w = fmaf(__uint_as_float(xA.y & 0xFFFF0000u), evA, aA0.w);
        aA1.x = fmaf(__uint_as_float(xA.z << 16),        evA, aA1.x);
        aA1.y = fmaf(__uint_as_float(xA.z & 0xFFFF0000u), evA, aA1.y);
        aA1.z = fmaf(__uint_as_float(xA.w << 16),        evA, aA1.z);
        aA1.w = fmaf(__uint_as_float(xA.w & 0xFFFF0000u), evA, aA1.w);

        aB0.x = fmaf(__uint_as_float(xB.x << 16),        evB, aB0.x);
        aB0.y = fmaf(__uint_as_float(xB.x & 0xFFFF0000u), evB, aB0.y);
        aB0.z = fmaf(__uint_as_float(xB.y << 16),        evB, aB0.z);
        aB0.w = fmaf(__uint_as_float(xB.y & 0xFFFF0000u), evB, aB0.w);
        aB1.x = fmaf(__uint_as_float(xB.z << 16),        evB, aB1.x);
        aB1.y = fmaf(__uint_as_float(xB.z & 0xFFFF0000u), evB, aB1.y);
        aB1.z = fmaf(__uint_as_float(xB.w << 16),        evB, aB1.z);
        aB1.w = fmaf(__uint_as_float(xB.w & 0xFFFF0000u), evB, aB1.w);
    }

    float4 a0 = make_float4(aA0.x + aB0.x, aA0.y + aB0.y,
                            aA0.z + aB0.z, aA0.w + aB0.w);
    float4 a1 = make_float4(aA1.x + aB1.x, aA1.y + aB1.y,
                            aA1.z + aB1.z, aA1.w + aB1.w);

#pragma unroll
    for (int m = 8; m < 64; m <<= 1) {
        a0.x += __shfl_xor(a0.x, m); a0.y += __shfl_xor(a0.y, m);
        a0.z += __shfl_xor(a0.z, m); a0.w += __shfl_xor(a0.w, m);
        a1.x += __shfl_xor(a1.x, m); a1.y += __shfl_xor(a1.y, m);
        a1.z += __shfl_xor(a1.z, m); a1.w += __shfl_xor(a1.w, m);
    }

    if (g == 0) {
        const float id = invdeg[node];
        float* __restrict__ srow = s + (size_t)node * F + q * 8;
        *(float4*)srow = make_float4(a0.x * id, a0.y * id, a0.z * id, a0.w * id);
        *(float4*)(srow + 4) = make_float4(a1.x * id, a1.y * id, a1.z * id, a1.w * id);
    }
}

// Block = 64 nodes x 4 waves. Stage x = [h|s] rows into LDS with coalesced
// loads (h from fp32 or bf16 shadow per IN_BF16), s always fp32. Wave wv
// computes output cols [wv*JT, ...) for all 64 nodes (lane = node), reading
// x from LDS (ds_read_b128) and W via wave-uniform s_load.
// OUT_BF16: write only the bf16 shadow row (next layer's gather + lin input).
template <int OUT, bool RELU, bool IN_BF16, bool OUT_BF16>
__global__ __launch_bounds__(256) void linear_lds_kernel(
    const float* __restrict__ hin_f, const unsigned short* __restrict__ hin_b,
    const float* __restrict__ s,
    const float* __restrict__ W, const float* __restrict__ b,
    float* __restrict__ out, unsigned short* __restrict__ hb_out, int n_nodes)
{
    constexpr int JT  = OUT / 4;   // j-tile per wave: 16 (lin1) / 8 (lin2)
    constexpr int STR = 132;       // row stride in floats (128 + 4, 16B-aligned)
    __shared__ float xin[64 * STR];

    const int tid   = threadIdx.x;
    const int node0 = blockIdx.x * 64;

    if constexpr (IN_BF16) {
        // stage h-half from bf16 shadow: 64 rows x 8 uint4 (8 bf16 each)
        for (int i = tid; i < 512; i += 256) {
            const int ln = i >> 3, c8 = i & 7;
            const int node = node0 + ln;
            uint4 v = make_uint4(0u, 0u, 0u, 0u);
            if (node < n_nodes)
                v = *(const uint4*)&hin_b[(size_t)node * F + c8 * 8];
            float4 lo = make_float4(__uint_as_float(v.x << 16),
                                    __uint_as_float(v.x & 0xFFFF0000u),
                                    __uint_as_float(v.y << 16),
                                    __uint_as_float(v.y & 0xFFFF0000u));
            float4 hi = make_float4(__uint_as_float(v.z << 16),
                                    __uint_as_float(v.z & 0xFFFF0000u),
                                    __uint_as_float(v.w << 16),
                                    __uint_as_float(v.w & 0xFFFF0000u));
            *(float4*)&xin[ln * STR + c8 * 8]     = lo;
            *(float4*)&xin[ln * STR + c8 * 8 + 4] = hi;
        }
    } else {
        // stage h-half: 64 rows x 16 float4 (coalesced)
        for (int i = tid; i < 1024; i += 256) {
            const int ln = i >> 4, c4 = i & 15;
            const int node = node0 + ln;
            float4 v = make_float4(0.f, 0.f, 0.f, 0.f);
            if (node < n_nodes)
                v = *(const float4*)&hin_f[(size_t)node * F + c4 * 4];
            *(float4*)&xin[ln * STR + c4 * 4] = v;
        }
    }
    // stage s-half
    for (int i = tid; i < 1024; i += 256) {
        const int ln = i >> 4, c4 = i & 15;
        const int node = node0 + ln;
        float4 v = make_float4(0.f, 0.f, 0.f, 0.f);
        if (node < n_nodes) v = *(const float4*)&s[(size_t)node * F + c4 * 4];
        *(float4*)&xin[ln * STR + F + c4 * 4] = v;
    }
    __syncthreads();

    const int lane = tid & 63;
    const int j0   = __builtin_amdgcn_readfirstlane((tid >> 6) * JT);

    float acc[JT];
#pragma unroll
    for (int j = 0; j < JT; ++j) acc[j] = b[j0 + j];

    const float* __restrict__ xrow = &xin[lane * STR];
#pragma unroll 2
    for (int k4 = 0; k4 < 32; ++k4) {
        const float4 xv = *(const float4*)&xrow[k4 * 4];
#pragma unroll
        for (int kk = 0; kk < 4; ++kk) {
            const int   k  = k4 * 4 + kk;
            const float xk = ((const float*)&xv)[kk];
#pragma unroll
            for (int j = 0; j < JT; ++j)
                acc[j] = fmaf(xk, W[k * OUT + j0 + j], acc[j]);
        }
    }

    const int node = node0 + lane;
    if (node < n_nodes) {
#pragma unroll
        for (int j = 0; j < JT; ++j) {
            float v = acc[j];
            if (RELU) v = fmaxf(v, 0.f);
            acc[j] = v;
        }
        if constexpr (OUT_BF16) {
            unsigned* __restrict__ hw =
                (unsigned*)(hb_out + (size_t)node * OUT + j0);
#pragma unroll
            for (int j = 0; j < JT; j += 2)
                hw[j >> 1] = bf16_rne(acc[j]) | (bf16_rne(acc[j + 1]) << 16);
        } else {
#pragma unroll
            for (int j = 0; j < JT; ++j)
                out[(size_t)node * OUT + j0 + j] = acc[j];
        }
    }
}

extern "C" void kernel_launch(void* const* d_in, const int* in_sizes, int n_in,
                              void* d_out, int out_size, void* d_ws, size_t ws_size,
                              hipStream_t stream)
{
    const float* in_feat   = (const float*)d_in[0];
    const float* edge_feat = (const float*)d_in[1];
    const int*   src       = (const int*)d_in[2];
    const int*   dst       = (const int*)d_in[3];
    const float* W1        = (const float*)d_in[4];
    const float* b1        = (const float*)d_in[5];
    const float* W2        = (const float*)d_in[6];
    const float* b2        = (const float*)d_in[7];
    float*       out       = (float*)d_out;

    const int n_nodes = in_sizes[0] / F;
    const int n_edges = in_sizes[2];
    const int nb      = (n_nodes + 63) >> 6;  // 64-node buckets

    // workspace layout (4-byte units)
    const int S = 100352;  // >= n_nodes+1, multiple of 256
    int*   wsi     = (int*)d_ws;
    int*   bcnt    = wsi;                     // [nb]
    int*   boff    = wsi + 2048;              // [nb+1]
    int*   bcursor = wsi + 4096;              // [nb]
    int*   off2    = wsi + 6144;              // [n_nodes+1]
    float* invdeg  = (float*)(wsi + 6144 + S);            // [n_nodes]
    int2*  brec    = (int2*)(wsi + 6144 + 2 * S);         // [n_edges]
    float* s       = (float*)(wsi + 6144 + 2 * S + 2 * (size_t)n_edges);
    unsigned short* hb = (unsigned short*)(s + (size_t)n_nodes * F); // [n*64] bf16

    hipMemsetAsync(bcnt, 0, (size_t)nb * sizeof(int), stream);

    const int egrid = (n_edges + EPB - 1) / EPB;
    bhist_kernel<<<egrid, TPB, 0, stream>>>(dst, bcnt, n_edges, nb);
    scan_kernel<<<1, 1024, 0, stream>>>(bcnt, boff, bcursor, nb);
    multisplit_kernel<<<egrid, TPB, 0, stream>>>(src, dst, edge_feat,
                                                 bcursor, brec, n_edges, nb);
    bucket_sort_kernel<<<nb, 256, 0, stream>>>(brec, boff, off2, invdeg,
                                               n_nodes, nb);

    const int n8    = (n_nodes * F) >> 3;               // elems/8
    const int cgrid = (n8 + 255) / 256;
    const int agrid = (int)(((size_t)n_nodes * 64 + 255) / 256);
    const int lgrid = (n_nodes + 63) / 64;

    // ---- layer 1 ----
    f32_to_bf16_kernel<<<cgrid, 256, 0, stream>>>(in_feat, hb, n8);
    agg_kernel<<<agrid, 256, 0, stream>>>(hb, brec, off2, invdeg, s, n_nodes);
    // lin1: reads in_feat(f32) + s, emits ONLY bf16 h1 into hb
    linear_lds_kernel<64, true, false, true><<<lgrid, 256, 0, stream>>>(
        in_feat, nullptr, s, W1, b1, nullptr, hb, n_nodes);

    // ---- layer 2 ----
    agg_kernel<<<agrid, 256, 0, stream>>>(hb, brec, off2, invdeg, s, n_nodes);
    // lin2: reads h1 from hb (bf16) + s, writes fp32 output
    linear_lds_kernel<32, false, true, false><<<lgrid, 256, 0, stream>>>(
        nullptr, hb, s, W2, b2, out, nullptr, n_nodes);
}